// Round 16
// baseline (822.963 us; speedup 1.0000x reference)
//
#include <hip/hip_runtime.h>

// Problem constants
#define BD   32768
#define NPG  54
#define NN   (BD * NPG)          // 1,769,472 nodes
#define NE   (BD * 144)          // 4,718,592 edges
#define DIN  16
#define DH   32
#define GLOBF 16
#define TBF  32                  // boards per final block
#define RB   256                 // nodes per dst bucket
#define NBK  (NN / RB)           // 6912 buckets
#define G8   8                   // writer groups (XCD proxy = (e>>8)&7)
#define HNB  (NBK * G8)          // 55296 (bucket,group) counters
#define QBK  (NBK / 4)           // quarter dispatches (profiling visibility)
#define QE   (NE / 4)
#define SRCM 0x1FFFFFu           // 21-bit src mask
#define CH   512                 // messages per sort-chunk
#define STW  20                  // conv1 sort-row stride (floats)
#define ST2  4                   // conv2 sort-row stride (floats)

// ---------------------------------------------------------------------------
// Pass 1: histogram over (dst-bucket, writer-group).  g=(e>>8)&7 is constant
// per 256-edge granule (= one place block) -> if dispatch round-robins blocks
// over XCDs, each (bk,g) sub-range is written by a single XCD.
// ---------------------------------------------------------------------------
__global__ __launch_bounds__(256) void k_hist8(const int* __restrict__ ei,
                                               unsigned* __restrict__ hist) {
  unsigned e = blockIdx.x * 256u + threadIdx.x;
  unsigned d = (unsigned)ei[NE + e];
  unsigned g = (e >> 8) & 7u;
  atomicAdd(&hist[(d >> 8) * G8 + g], 1u);               // fire-and-forget
}

// ---------------------------------------------------------------------------
// Pass 2: exclusive scan of 55296 counts (single block, 54 per thread)
// ---------------------------------------------------------------------------
__global__ __launch_bounds__(1024) void k_scan8(const unsigned* __restrict__ hist,
                                                unsigned* __restrict__ base,
                                                unsigned* __restrict__ cursor) {
  __shared__ unsigned s[1024];
  const int tid = threadIdx.x;
  unsigned run = 0;
  for (int j = 0; j < 54; ++j) run += hist[tid * 54 + j];
  s[tid] = run; __syncthreads();
  for (int off = 1; off < 1024; off <<= 1) {
    unsigned t = (tid >= off) ? s[tid - off] : 0u;
    __syncthreads(); s[tid] += t; __syncthreads();
  }
  unsigned run2 = tid ? s[tid - 1] : 0u;
  for (int j = 0; j < 54; ++j) {
    unsigned idx = tid * 54 + j;
    unsigned v = hist[idx];
    base[idx] = run2; cursor[idx] = run2; run2 += v;
  }
  if (tid == 1023) base[HNB] = run2;                     // = NE
}

// ---------------------------------------------------------------------------
// Pass 3: place records dst-bucket-sorted into the (bk,g) sub-range
// ---------------------------------------------------------------------------
__global__ __launch_bounds__(256) void k_place8(const int* __restrict__ ei,
                                                const float* __restrict__ ea,
                                                unsigned* __restrict__ cursor,
                                                uint2* __restrict__ rec,
                                                unsigned e0) {
  unsigned e = e0 + blockIdx.x * 256u + threadIdx.x;
  unsigned s = (unsigned)ei[e];
  unsigned d = (unsigned)ei[NE + e];
  float w = ea[e];
  unsigned g = (e >> 8) & 7u;
  unsigned pos = atomicAdd(&cursor[(d >> 8) * G8 + g], 1u);
  rec[pos] = make_uint2(s | ((d & 255u) << 21), __float_as_uint(w));
}

// shfl-based exclusive scan helper (256 threads, packed 16+16 fields)
__device__ __forceinline__ unsigned block_excl_scan_packed(
    unsigned packed, unsigned* wsum, int tid) {
  unsigned v = packed;
#pragma unroll
  for (int off = 1; off < 64; off <<= 1) {
    unsigned t = __shfl_up(v, off, 64);
    if ((tid & 63) >= off) v += t;
  }
  if ((tid & 63) == 63) wsum[tid >> 6] = v;
  __syncthreads();
  const int wid = tid >> 6;
  unsigned wpre = 0;
#pragma unroll
  for (int wmid = 0; wmid < 4; ++wmid)
    if (wmid < wid) wpre += wsum[wmid];
  return v + wpre - packed;            // exclusive
}

// ---------------------------------------------------------------------------
// Conv1 (dual counting sort, shfl scan): gather in ascending-src order,
// scatter dst-sorted, per-node contiguous sum, fused transform -> z2, r2
// ---------------------------------------------------------------------------
__global__ __launch_bounds__(256) void k_conv1s(
    const uint2* __restrict__ rec, const unsigned* __restrict__ base,
    const float* __restrict__ x,
    const float* __restrict__ W1_rel, const float* __restrict__ b1,
    const float* __restrict__ W1_root,
    const float* __restrict__ W2_rel, const float* __restrict__ b2,
    const float* __restrict__ W2_root,
    float* __restrict__ z2, float* __restrict__ r2, unsigned bkoff) {
  __shared__ float buf[CH * STW];        // 40960 B
  __shared__ uint2 prm[CH];              // 4096 B
  __shared__ unsigned hd[256];
  __shared__ unsigned hs[256];
  __shared__ unsigned sc[256];
  __shared__ unsigned wsum[4];
  const int tid = threadIdx.x;
  const unsigned bk = blockIdx.x + bkoff;
  const unsigned r0 = base[bk * G8], r1 = base[bk * G8 + G8];

  float a[16];
#pragma unroll
  for (int i = 0; i < 16; ++i) a[i] = 0.f;

  for (unsigned c0 = r0; c0 < r1; c0 += CH) {
    const unsigned validCnt = min((unsigned)CH, r1 - c0);
    hd[tid] = 0u; hs[tid] = 0u;
    __syncthreads();

    const unsigned i0 = c0 + tid;
    const unsigned i1 = c0 + 256u + tid;
    const bool qa = i0 < r1;
    const bool qb = i1 < r1;
    unsigned srcA = 0, srcB = 0, la = 0, lb = 0, sa = 0, sb = 0;
    unsigned wa = 0, wb = 0, rkda = 0, rkdb = 0, rksa = 0, rksb = 0;
    if (qa) {
      uint2 ra = rec[i0];
      srcA = ra.x & SRCM; la = ra.x >> 21; sa = srcA >> 13; wa = ra.y;
    }
    if (qb) {
      uint2 rb = rec[i1];
      srcB = rb.x & SRCM; lb = rb.x >> 21; sb = srcB >> 13; wb = rb.y;
    }
    if (qa) { rkda = atomicAdd(&hd[la], 1u); rksa = atomicAdd(&hs[sa], 1u); }
    if (qb) { rkdb = atomicAdd(&hd[lb], 1u); rksb = atomicAdd(&hs[sb], 1u); }
    __syncthreads();

    const unsigned cd = hd[tid];
    const unsigned packed = cd | (hs[tid] << 16);
    const unsigned exclP = block_excl_scan_packed(packed, wsum, tid);
    const unsigned myoff = exclP & 0xffffu;
    sc[tid] = exclP;
    __syncthreads();

    if (qa) {
      unsigned dslot = (sc[la] & 0xffffu) + rkda;
      unsigned spos  = (sc[sa] >> 16) + rksa;
      prm[spos] = make_uint2(srcA | (dslot << 21), wa);
    }
    if (qb) {
      unsigned dslot = (sc[lb] & 0xffffu) + rkdb;
      unsigned spos  = (sc[sb] >> 16) + rksb;
      prm[spos] = make_uint2(srcB | (dslot << 21), wb);
    }
    __syncthreads();

    // gather phase in ascending-src order
    {
      const bool ga = tid < validCnt;
      const bool gb = tid + 256u < validCnt;
      uint2 pa, pb;
      float4 xa0, xa1, xa2, xa3, xb0, xb1, xb2, xb3;
      if (ga) {
        pa = prm[tid];
        const float4* xp = reinterpret_cast<const float4*>(x + (size_t)(pa.x & SRCM) * 16);
        xa0 = xp[0]; xa1 = xp[1]; xa2 = xp[2]; xa3 = xp[3];
      }
      if (gb) {
        pb = prm[tid + 256];
        const float4* xp = reinterpret_cast<const float4*>(x + (size_t)(pb.x & SRCM) * 16);
        xb0 = xp[0]; xb1 = xp[1]; xb2 = xp[2]; xb3 = xp[3];
      }
      if (ga) {
        float w = __uint_as_float(pa.y);
        float* bp = buf + (size_t)(pa.x >> 21) * STW;
        reinterpret_cast<float4*>(bp)[0] = make_float4(xa0.x*w, xa0.y*w, xa0.z*w, xa0.w*w);
        reinterpret_cast<float4*>(bp)[1] = make_float4(xa1.x*w, xa1.y*w, xa1.z*w, xa1.w*w);
        reinterpret_cast<float4*>(bp)[2] = make_float4(xa2.x*w, xa2.y*w, xa2.z*w, xa2.w*w);
        reinterpret_cast<float4*>(bp)[3] = make_float4(xa3.x*w, xa3.y*w, xa3.z*w, xa3.w*w);
      }
      if (gb) {
        float w = __uint_as_float(pb.y);
        float* bp = buf + (size_t)(pb.x >> 21) * STW;
        reinterpret_cast<float4*>(bp)[0] = make_float4(xb0.x*w, xb0.y*w, xb0.z*w, xb0.w*w);
        reinterpret_cast<float4*>(bp)[1] = make_float4(xb1.x*w, xb1.y*w, xb1.z*w, xb1.w*w);
        reinterpret_cast<float4*>(bp)[2] = make_float4(xb2.x*w, xb2.y*w, xb2.z*w, xb2.w*w);
        reinterpret_cast<float4*>(bp)[3] = make_float4(xb3.x*w, xb3.y*w, xb3.z*w, xb3.w*w);
      }
    }
    __syncthreads();

    for (unsigned k = 0; k < cd; ++k) {
      const float* bp = buf + (size_t)(myoff + k) * STW;
      float4 m0 = reinterpret_cast<const float4*>(bp)[0];
      float4 m1 = reinterpret_cast<const float4*>(bp)[1];
      float4 m2 = reinterpret_cast<const float4*>(bp)[2];
      float4 m3 = reinterpret_cast<const float4*>(bp)[3];
      a[0]  += m0.x; a[1]  += m0.y; a[2]  += m0.z; a[3]  += m0.w;
      a[4]  += m1.x; a[5]  += m1.y; a[6]  += m1.z; a[7]  += m1.w;
      a[8]  += m2.x; a[9]  += m2.y; a[10] += m2.z; a[11] += m2.w;
      a[12] += m3.x; a[13] += m3.y; a[14] += m3.z; a[15] += m3.w;
    }
    __syncthreads();
  }

  // fused node transform
  size_t n = (size_t)bk * RB + tid;
  float xv[16];
  {
    const float4* xp = reinterpret_cast<const float4*>(x + n * 16);
#pragma unroll
    for (int q = 0; q < 4; ++q) {
      float4 t2 = xp[q];
      xv[4*q+0] = t2.x; xv[4*q+1] = t2.y; xv[4*q+2] = t2.z; xv[4*q+3] = t2.w;
    }
  }
  float h[DH];
#pragma unroll
  for (int j = 0; j < DH; ++j) h[j] = b1[j];
#pragma unroll
  for (int i = 0; i < DIN; ++i) {
    float ai = a[i], xi = xv[i];
#pragma unroll
    for (int j = 0; j < DH; ++j)
      h[j] = fmaf(ai, W1_rel[i * DH + j], fmaf(xi, W1_root[i * DH + j], h[j]));
  }
#pragma unroll
  for (int j = 0; j < DH; ++j) h[j] = fmaxf(h[j], 0.f);
  float z[4] = {0.f, 0.f, 0.f, 0.f};
  float r[4] = {b2[0], b2[1], b2[2], b2[3]};
#pragma unroll
  for (int j = 0; j < DH; ++j) {
    float hj = h[j];
#pragma unroll
    for (int k = 0; k < 4; ++k) {
      z[k] = fmaf(hj, W2_rel[j * 4 + k], z[k]);
      r[k] = fmaf(hj, W2_root[j * 4 + k], r[k]);
    }
  }
  *reinterpret_cast<float4*>(z2 + n * 4) = make_float4(z[0], z[1], z[2], z[3]);
  *reinterpret_cast<float4*>(r2 + n * 4) = make_float4(r[0], r[1], r[2], r[3]);
}

// ---------------------------------------------------------------------------
// Conv2 (dual counting sort, shfl scan, 16B rows): embeds = relu(sum + r2)
// ---------------------------------------------------------------------------
__global__ __launch_bounds__(256) void k_conv2s(
    const uint2* __restrict__ rec, const unsigned* __restrict__ base,
    const float* __restrict__ z2, const float* __restrict__ r2,
    float* __restrict__ embeds, unsigned bkoff) {
  __shared__ float buf[CH * ST2];
  __shared__ uint2 prm[CH];
  __shared__ unsigned hd[256];
  __shared__ unsigned hs[256];
  __shared__ unsigned sc[256];
  __shared__ unsigned wsum[4];
  const int tid = threadIdx.x;
  const unsigned bk = blockIdx.x + bkoff;
  const unsigned r0 = base[bk * G8], r1 = base[bk * G8 + G8];

  float4 a = make_float4(0.f, 0.f, 0.f, 0.f);

  for (unsigned c0 = r0; c0 < r1; c0 += CH) {
    const unsigned validCnt = min((unsigned)CH, r1 - c0);
    hd[tid] = 0u; hs[tid] = 0u;
    __syncthreads();

    const unsigned i0 = c0 + tid;
    const unsigned i1 = c0 + 256u + tid;
    const bool qa = i0 < r1;
    const bool qb = i1 < r1;
    unsigned srcA = 0, srcB = 0, la = 0, lb = 0, sa = 0, sb = 0;
    unsigned wa = 0, wb = 0, rkda = 0, rkdb = 0, rksa = 0, rksb = 0;
    if (qa) {
      uint2 ra = rec[i0];
      srcA = ra.x & SRCM; la = ra.x >> 21; sa = srcA >> 13; wa = ra.y;
    }
    if (qb) {
      uint2 rb = rec[i1];
      srcB = rb.x & SRCM; lb = rb.x >> 21; sb = srcB >> 13; wb = rb.y;
    }
    if (qa) { rkda = atomicAdd(&hd[la], 1u); rksa = atomicAdd(&hs[sa], 1u); }
    if (qb) { rkdb = atomicAdd(&hd[lb], 1u); rksb = atomicAdd(&hs[sb], 1u); }
    __syncthreads();

    const unsigned cd = hd[tid];
    const unsigned packed = cd | (hs[tid] << 16);
    const unsigned exclP = block_excl_scan_packed(packed, wsum, tid);
    const unsigned myoff = exclP & 0xffffu;
    sc[tid] = exclP;
    __syncthreads();

    if (qa) {
      unsigned dslot = (sc[la] & 0xffffu) + rkda;
      unsigned spos  = (sc[sa] >> 16) + rksa;
      prm[spos] = make_uint2(srcA | (dslot << 21), wa);
    }
    if (qb) {
      unsigned dslot = (sc[lb] & 0xffffu) + rkdb;
      unsigned spos  = (sc[sb] >> 16) + rksb;
      prm[spos] = make_uint2(srcB | (dslot << 21), wb);
    }
    __syncthreads();

    {
      const bool ga = tid < validCnt;
      const bool gb = tid + 256u < validCnt;
      uint2 pa, pb;
      float4 za, zb;
      if (ga) {
        pa = prm[tid];
        za = *reinterpret_cast<const float4*>(z2 + (size_t)(pa.x & SRCM) * 4);
      }
      if (gb) {
        pb = prm[tid + 256];
        zb = *reinterpret_cast<const float4*>(z2 + (size_t)(pb.x & SRCM) * 4);
      }
      if (ga) {
        float w = __uint_as_float(pa.y);
        *reinterpret_cast<float4*>(buf + (size_t)(pa.x >> 21) * ST2) =
            make_float4(za.x*w, za.y*w, za.z*w, za.w*w);
      }
      if (gb) {
        float w = __uint_as_float(pb.y);
        *reinterpret_cast<float4*>(buf + (size_t)(pb.x >> 21) * ST2) =
            make_float4(zb.x*w, zb.y*w, zb.z*w, zb.w*w);
      }
    }
    __syncthreads();

    for (unsigned k = 0; k < cd; ++k) {
      float4 m = *reinterpret_cast<const float4*>(buf + (size_t)(myoff + k) * ST2);
      a.x += m.x; a.y += m.y; a.z += m.z; a.w += m.w;
    }
    __syncthreads();
  }

  size_t n = (size_t)bk * RB + tid;
  const float4 rr = *reinterpret_cast<const float4*>(r2 + n * 4);
  float4 o;
  o.x = fmaxf(a.x + rr.x, 0.f);
  o.y = fmaxf(a.y + rr.y, 0.f);
  o.z = fmaxf(a.z + rr.z, 0.f);
  o.w = fmaxf(a.w + rr.w, 0.f);
  *reinterpret_cast<float4*>(embeds + n * 4) = o;
}

// ---------------------------------------------------------------------------
// Final MLP (unchanged from round 15: TBF=32, r=4, prefetch, lb(256,2))
// ---------------------------------------------------------------------------
__global__ __launch_bounds__(256, 2) void k_final(
    const float* __restrict__ embeds, const float* __restrict__ gfeat,
    const float* __restrict__ Wg1, const float* __restrict__ bg1,
    const float* __restrict__ Wg2, const float* __restrict__ bg2,
    const float* __restrict__ Wg3, const float* __restrict__ bg3,
    const float* __restrict__ Wo1, const float* __restrict__ bo1,
    const float* __restrict__ Wo2, const float* __restrict__ bo2,
    const float* __restrict__ Wo3, const float* __restrict__ bo3,
    float* __restrict__ out) {
  __shared__ float svec[TBF * 232];
  __shared__ float sbuf1[TBF * 128];
  float* sbuf2 = svec;

  const int tid = threadIdx.x;
  const int b0  = blockIdx.x * TBF;

  {
    const float4* src = reinterpret_cast<const float4*>(embeds + (size_t)b0 * 216);
    for (int f4i = tid; f4i < TBF * 54; f4i += 256) {
      int b = f4i / 54;
      int k4 = f4i - b * 54;
      *reinterpret_cast<float4*>(svec + b * 232 + k4 * 4) = src[f4i];
    }
  }
  if (tid < TBF) {
    const float* gf = gfeat + (size_t)(b0 + tid) * GLOBF;
    float gin[16];
#pragma unroll
    for (int i = 0; i < 16; ++i) gin[i] = gf[i];
    float g1[8];
#pragma unroll
    for (int j = 0; j < 8; ++j) {
      float acc = bg1[j];
#pragma unroll
      for (int i = 0; i < 16; ++i) acc = fmaf(gin[i], Wg1[i * 8 + j], acc);
      g1[j] = fmaxf(acc, 0.f);
    }
    float g2[8];
#pragma unroll
    for (int j = 0; j < 8; ++j) {
      float acc = bg2[j];
#pragma unroll
      for (int i = 0; i < 8; ++i) acc = fmaf(g1[i], Wg2[i * 8 + j], acc);
      g2[j] = fmaxf(acc, 0.f);
    }
#pragma unroll
    for (int j = 0; j < 16; ++j) {
      float acc = bg3[j];
#pragma unroll
      for (int i = 0; i < 8; ++i) acc = fmaf(g2[i], Wg3[i * 16 + j], acc);
      svec[tid * 232 + 216 + j] = fmaxf(acc, 0.f);
    }
  }
  __syncthreads();

  const int c0 = (tid & 31) * 4;
  const int rb = (tid >> 5) * 4;

  {
    const float* Wp = Wo1 + c0;
    float4 w0 = *reinterpret_cast<const float4*>(Wp + 0 * 128);
    float4 w1 = *reinterpret_cast<const float4*>(Wp + 1 * 128);
    float4 w2 = *reinterpret_cast<const float4*>(Wp + 2 * 128);
    float4 w3 = *reinterpret_cast<const float4*>(Wp + 3 * 128);
    float acc[4][4];
#pragma unroll
    for (int r = 0; r < 4; ++r)
#pragma unroll
      for (int c = 0; c < 4; ++c) acc[r][c] = 0.f;
    for (int i4 = 0; i4 < 58; ++i4) {
      float4 n0, n1, n2, n3;
      if (i4 < 57) {
        const float* Np = Wp + (size_t)(i4 * 4 + 4) * 128;
        n0 = *reinterpret_cast<const float4*>(Np + 0 * 128);
        n1 = *reinterpret_cast<const float4*>(Np + 1 * 128);
        n2 = *reinterpret_cast<const float4*>(Np + 2 * 128);
        n3 = *reinterpret_cast<const float4*>(Np + 3 * 128);
      }
#pragma unroll
      for (int r = 0; r < 4; ++r) {
        const float4 s = *reinterpret_cast<const float4*>(svec + (rb+r)*232 + i4*4);
        acc[r][0] = fmaf(s.x, w0.x, fmaf(s.y, w1.x, fmaf(s.z, w2.x, fmaf(s.w, w3.x, acc[r][0]))));
        acc[r][1] = fmaf(s.x, w0.y, fmaf(s.y, w1.y, fmaf(s.z, w2.y, fmaf(s.w, w3.y, acc[r][1]))));
        acc[r][2] = fmaf(s.x, w0.z, fmaf(s.y, w1.z, fmaf(s.z, w2.z, fmaf(s.w, w3.z, acc[r][2]))));
        acc[r][3] = fmaf(s.x, w0.w, fmaf(s.y, w1.w, fmaf(s.z, w2.w, fmaf(s.w, w3.w, acc[r][3]))));
      }
      w0 = n0; w1 = n1; w2 = n2; w3 = n3;
    }
    const float4 bv = *reinterpret_cast<const float4*>(bo1 + c0);
#pragma unroll
    for (int r = 0; r < 4; ++r) {
      float4 o;
      o.x = fmaxf(acc[r][0] + bv.x, 0.f);
      o.y = fmaxf(acc[r][1] + bv.y, 0.f);
      o.z = fmaxf(acc[r][2] + bv.z, 0.f);
      o.w = fmaxf(acc[r][3] + bv.w, 0.f);
      *reinterpret_cast<float4*>(sbuf1 + (rb + r) * 128 + c0) = o;
    }
  }
  __syncthreads();

  {
    const float* Wp = Wo2 + c0;
    float4 w0 = *reinterpret_cast<const float4*>(Wp + 0 * 128);
    float4 w1 = *reinterpret_cast<const float4*>(Wp + 1 * 128);
    float4 w2 = *reinterpret_cast<const float4*>(Wp + 2 * 128);
    float4 w3 = *reinterpret_cast<const float4*>(Wp + 3 * 128);
    float acc[4][4];
#pragma unroll
    for (int r = 0; r < 4; ++r)
#pragma unroll
      for (int c = 0; c < 4; ++c) acc[r][c] = 0.f;
    for (int i4 = 0; i4 < 32; ++i4) {
      float4 n0, n1, n2, n3;
      if (i4 < 31) {
        const float* Np = Wp + (size_t)(i4 * 4 + 4) * 128;
        n0 = *reinterpret_cast<const float4*>(Np + 0 * 128);
        n1 = *reinterpret_cast<const float4*>(Np + 1 * 128);
        n2 = *reinterpret_cast<const float4*>(Np + 2 * 128);
        n3 = *reinterpret_cast<const float4*>(Np + 3 * 128);
      }
#pragma unroll
      for (int r = 0; r < 4; ++r) {
        const float4 s = *reinterpret_cast<const float4*>(sbuf1 + (rb+r)*128 + i4*4);
        acc[r][0] = fmaf(s.x, w0.x, fmaf(s.y, w1.x, fmaf(s.z, w2.x, fmaf(s.w, w3.x, acc[r][0]))));
        acc[r][1] = fmaf(s.x, w0.y, fmaf(s.y, w1.y, fmaf(s.z, w2.y, fmaf(s.w, w3.y, acc[r][1]))));
        acc[r][2] = fmaf(s.x, w0.z, fmaf(s.y, w1.z, fmaf(s.z, w2.z, fmaf(s.w, w3.z, acc[r][2]))));
        acc[r][3] = fmaf(s.x, w0.w, fmaf(s.y, w1.w, fmaf(s.z, w2.w, fmaf(s.w, w3.w, acc[r][3]))));
      }
      w0 = n0; w1 = n1; w2 = n2; w3 = n3;
    }
    const float4 bv = *reinterpret_cast<const float4*>(bo2 + c0);
#pragma unroll
    for (int r = 0; r < 4; ++r) {
      float4 o;
      o.x = fmaxf(acc[r][0] + bv.x, 0.f);
      o.y = fmaxf(acc[r][1] + bv.y, 0.f);
      o.z = fmaxf(acc[r][2] + bv.z, 0.f);
      o.w = fmaxf(acc[r][3] + bv.w, 0.f);
      *reinterpret_cast<float4*>(sbuf2 + (rb + r) * 128 + c0) = o;
    }
  }
  __syncthreads();

  {
    const int c2 = (tid & 31) * 2;
    const float* Wp = Wo3 + c2;
    float2 w0 = *reinterpret_cast<const float2*>(Wp + 0 * 64);
    float2 w1 = *reinterpret_cast<const float2*>(Wp + 1 * 64);
    float2 w2 = *reinterpret_cast<const float2*>(Wp + 2 * 64);
    float2 w3 = *reinterpret_cast<const float2*>(Wp + 3 * 64);
    float acc[4][2];
#pragma unroll
    for (int r = 0; r < 4; ++r) { acc[r][0] = 0.f; acc[r][1] = 0.f; }
    for (int i4 = 0; i4 < 32; ++i4) {
      float2 n0, n1, n2, n3;
      if (i4 < 31) {
        const float* Np = Wp + (size_t)(i4 * 4 + 4) * 64;
        n0 = *reinterpret_cast<const float2*>(Np + 0 * 64);
        n1 = *reinterpret_cast<const float2*>(Np + 1 * 64);
        n2 = *reinterpret_cast<const float2*>(Np + 2 * 64);
        n3 = *reinterpret_cast<const float2*>(Np + 3 * 64);
      }
#pragma unroll
      for (int r = 0; r < 4; ++r) {
        const float4 s = *reinterpret_cast<const float4*>(sbuf2 + (rb+r)*128 + i4*4);
        acc[r][0] = fmaf(s.x, w0.x, fmaf(s.y, w1.x, fmaf(s.z, w2.x, fmaf(s.w, w3.x, acc[r][0]))));
        acc[r][1] = fmaf(s.x, w0.y, fmaf(s.y, w1.y, fmaf(s.z, w2.y, fmaf(s.w, w3.y, acc[r][1]))));
      }
      w0 = n0; w1 = n1; w2 = n2; w3 = n3;
    }
    const float2 bv = *reinterpret_cast<const float2*>(bo3 + c2);
#pragma unroll
    for (int r = 0; r < 4; ++r) {
      float2 o;
      o.x = acc[r][0] + bv.x;
      o.y = acc[r][1] + bv.y;
      *reinterpret_cast<float2*>(out + (size_t)(b0 + rb + r) * 64 + c2) = o;
    }
  }
}

// ---------------------------------------------------------------------------
extern "C" void kernel_launch(void* const* d_in, const int* in_sizes, int n_in,
                              void* d_out, int out_size, void* d_ws, size_t ws_size,
                              hipStream_t stream) {
  const float* x      = (const float*)d_in[0];
  const int*   ei     = (const int*)d_in[1];
  const float* ea     = (const float*)d_in[2];
  const float* gfeat  = (const float*)d_in[3];
  const float* W1_rel = (const float*)d_in[5];
  const float* b1     = (const float*)d_in[6];
  const float* W1_root= (const float*)d_in[7];
  const float* W2_rel = (const float*)d_in[8];
  const float* b2     = (const float*)d_in[9];
  const float* W2_root= (const float*)d_in[10];
  const float* Wg1 = (const float*)d_in[11];
  const float* bg1 = (const float*)d_in[12];
  const float* Wg2 = (const float*)d_in[13];
  const float* bg2 = (const float*)d_in[14];
  const float* Wg3 = (const float*)d_in[15];
  const float* bg3 = (const float*)d_in[16];
  const float* Wo1 = (const float*)d_in[17];
  const float* bo1 = (const float*)d_in[18];
  const float* Wo2 = (const float*)d_in[19];
  const float* bo2 = (const float*)d_in[20];
  const float* Wo3 = (const float*)d_in[21];
  const float* bo3 = (const float*)d_in[22];
  float* outp = (float*)d_out;

  // workspace (~124 MB)
  uint2*    rec    = (uint2*)d_ws;                       // NE*8B
  float*    z2     = (float*)(rec + NE);                 // NN*4 f
  float*    r2     = z2 + (size_t)NN * 4;                // NN*4 f
  float*    embeds = r2 + (size_t)NN * 4;                // NN*4 f
  unsigned* hist   = (unsigned*)(embeds + (size_t)NN * 4); // HNB
  unsigned* base   = hist + HNB;                         // HNB+1
  unsigned* cursor = base + HNB + 1;                     // HNB

  hipMemsetAsync(hist, 0, HNB * sizeof(unsigned), stream);
  k_hist8<<<NE / 256, 256, 0, stream>>>(ei, hist);
  k_scan8<<<1, 1024, 0, stream>>>(hist, base, cursor);
  for (unsigned q = 0; q < 4; ++q)
    k_place8<<<QE / 256, 256, 0, stream>>>(ei, ea, cursor, rec, q * QE);
  for (unsigned q = 0; q < 4; ++q)
    k_conv1s<<<QBK, 256, 0, stream>>>(rec, base, x, W1_rel, b1, W1_root,
                                      W2_rel, b2, W2_root, z2, r2, q * QBK);
  for (unsigned q = 0; q < 4; ++q)
    k_conv2s<<<QBK, 256, 0, stream>>>(rec, base, z2, r2, embeds, q * QBK);
  k_final<<<BD / TBF, 256, 0, stream>>>(embeds, gfeat,
                                        Wg1, bg1, Wg2, bg2, Wg3, bg3,
                                        Wo1, bo1, Wo2, bo2, Wo3, bo3, outp);
}

// Round 17
// 499.150 us; speedup vs baseline: 1.6487x; 1.6487x over previous
//
#include <hip/hip_runtime.h>

// Problem constants
#define BD   32768
#define NPG  54
#define NN   (BD * NPG)          // 1,769,472 nodes
#define NE   (BD * 144)          // 4,718,592 edges
#define DIN  16
#define DH   32
#define GLOBF 16
#define TBF  32                  // boards per final block
#define RB   256                 // nodes per dst bucket
#define NBK  (NN / RB)           // 6912 buckets
#define QBK  (NBK / 4)
#define SRCM 0x1FFFFFu           // 21-bit src mask
#define CH   512                 // conv sort-chunk
#define STW  20
#define ST2  4
#define HB   256                 // hist blocks
#define EB   4096                // edges per place block
#define NBA  (NE / EB)           // 1152
#define NCL  108                 // classes = d>>14 (64 buckets each; 108*16384=NN)
#define CPB  12                  // placeB chunks per class (12*4096 >= max class)

// ---------------------------------------------------------------------------
// Pass 1: dst-bucket histogram (LDS-staged; known-good)
// ---------------------------------------------------------------------------
__global__ __launch_bounds__(256) void k_histl(const int* __restrict__ ei,
                                               unsigned* __restrict__ hist) {
  __shared__ unsigned h[NBK];                            // 27648 B
  const int tid = threadIdx.x;
  for (int i = tid; i < NBK; i += 256) h[i] = 0u;
  __syncthreads();
  const unsigned base = blockIdx.x * (NE / HB);
  for (unsigned i = tid; i < NE / HB; i += 256u) {
    unsigned d = (unsigned)ei[NE + base + i];
    atomicAdd(&h[d >> 8], 1u);
  }
  __syncthreads();
  for (int i = tid; i < NBK; i += 256)
    if (h[i]) atomicAdd(&hist[i], h[i]);
}

// ---------------------------------------------------------------------------
// Pass 2: exclusive scan of 6912 bucket counts; also inits class cursors
// (curA[c] = base[c*64]) for placeA.
// ---------------------------------------------------------------------------
__global__ __launch_bounds__(1024) void k_scan2(const unsigned* __restrict__ hist,
                                                unsigned* __restrict__ base,
                                                unsigned* __restrict__ cursorB,
                                                unsigned* __restrict__ curA) {
  __shared__ unsigned s[1024];
  const int tid = threadIdx.x;
  unsigned loc[7]; unsigned run = 0;
#pragma unroll
  for (int j = 0; j < 7; ++j) {
    int idx = tid * 7 + j;
    unsigned v = (idx < NBK) ? hist[idx] : 0u;
    loc[j] = run; run += v;
  }
  s[tid] = run; __syncthreads();
  for (int off = 1; off < 1024; off <<= 1) {
    unsigned t = (tid >= off) ? s[tid - off] : 0u;
    __syncthreads(); s[tid] += t; __syncthreads();
  }
  unsigned cb = tid ? s[tid - 1] : 0u;
#pragma unroll
  for (int j = 0; j < 7; ++j) {
    int idx = tid * 7 + j;
    if (idx < NBK) {
      unsigned b = cb + loc[j];
      base[idx] = b; cursorB[idx] = b;
      if ((idx & 63) == 0) curA[idx >> 6] = b;           // class base
    }
  }
  if (tid == 1023) base[NBK] = s[1023];                  // = NE
}

// ---------------------------------------------------------------------------
// placeA: LDS counting sort of 4096 edges by class (d>>14), flush per-class
// RUNS (~38 records) via one cursor claim each -> recA (+dhiA byte payload).
// Run-claims make writes line-contiguous: write-amp ~1.2 vs 7x per-record.
// ---------------------------------------------------------------------------
__global__ __launch_bounds__(256) void k_placeA(
    const int* __restrict__ ei, const float* __restrict__ ea,
    unsigned* __restrict__ curA, uint2* __restrict__ recA,
    unsigned char* __restrict__ dhiA) {
  __shared__ uint2 buf[EB];                              // 32768 B
  __shared__ unsigned char cls8[EB];                     // 4096 B
  __shared__ unsigned char dh6[EB];                      // 4096 B
  __shared__ unsigned h[NCL];
  __shared__ unsigned sb[NCL];
  __shared__ unsigned posL[NCL];
  const int tid = threadIdx.x;
  const unsigned eb = blockIdx.x * (unsigned)EB;

  for (int k = tid; k < NCL; k += 256) h[k] = 0u;
  __syncthreads();

  unsigned rkcls[16];                                    // rank(12b) | class<<12
#pragma unroll
  for (int i = 0; i < 16; ++i) {
    unsigned e = eb + i * 256u + tid;                    // coalesced
    unsigned d = (unsigned)ei[NE + e];
    unsigned c = d >> 14;
    unsigned rk = atomicAdd(&h[c], 1u);
    rkcls[i] = rk | (c << 12);
  }
  __syncthreads();
  if (tid == 0) {
    unsigned runl = 0;
    for (int k = 0; k < NCL; ++k) { sb[k] = runl; runl += h[k]; }
  }
  if (tid < NCL && tid >= 0) { /* claims below need final h only */ }
  __syncthreads();
  if (tid < NCL) posL[tid] = atomicAdd(&curA[tid], h[tid]);
  __syncthreads();

  // scatter sorted (re-read edges; chunk is L1/L2-hot)
#pragma unroll
  for (int i = 0; i < 16; ++i) {
    unsigned e = eb + i * 256u + tid;
    unsigned sv = (unsigned)ei[e];
    unsigned d  = (unsigned)ei[NE + e];
    float    w  = ea[e];
    unsigned c  = rkcls[i] >> 12;
    unsigned slot = sb[c] + (rkcls[i] & 0xFFFu);
    buf[slot]  = make_uint2(sv | ((d & 255u) << 21), __float_as_uint(w));
    cls8[slot] = (unsigned char)c;
    dh6[slot]  = (unsigned char)((d >> 8) & 63u);
  }
  __syncthreads();

  // flush contiguous runs
  for (int i = tid; i < EB; i += 256) {
    unsigned c = cls8[i];
    unsigned pos = posL[c] + (unsigned)i - sb[c];
    recA[pos] = buf[i];
    dhiA[pos] = dh6[i];
  }
}

// ---------------------------------------------------------------------------
// placeB: within one class, LDS counting sort of a 4096-record chunk by
// bucket-in-class (dhiA), flush per-bucket RUNS (~64 records = 512B) -> rec.
// ---------------------------------------------------------------------------
__global__ __launch_bounds__(256) void k_placeB(
    const uint2* __restrict__ recA, const unsigned char* __restrict__ dhiA,
    const unsigned* __restrict__ base, unsigned* __restrict__ curB,
    uint2* __restrict__ rec) {
  __shared__ uint2 buf[EB];                              // 32768 B
  __shared__ unsigned char dh6[EB];                      // 4096 B
  __shared__ unsigned h[64];
  __shared__ unsigned sb[64];
  __shared__ unsigned posL[64];
  const int tid = threadIdx.x;
  const unsigned c = blockIdx.x / CPB;
  const unsigned j = blockIdx.x % CPB;
  const unsigned clsLo = base[c * 64];
  const unsigned clsHi = base[c * 64 + 64];
  const unsigned lo = clsLo + j * (unsigned)EB;
  if (lo >= clsHi) return;                               // uniform exit
  const unsigned hi = min(lo + (unsigned)EB, clsHi);
  const unsigned cnt = hi - lo;

  if (tid < 64) h[tid] = 0u;
  __syncthreads();

  unsigned rkd[16];
#pragma unroll
  for (int i = 0; i < 16; ++i) {
    unsigned idx = lo + i * 256u + tid;
    rkd[i] = 0xFFFFFFFFu;
    if (idx < hi) {
      unsigned dh = dhiA[idx];
      unsigned rk = atomicAdd(&h[dh], 1u);
      rkd[i] = rk | (dh << 12);
    }
  }
  __syncthreads();
  if (tid == 0) {
    unsigned runl = 0;
    for (int k = 0; k < 64; ++k) { sb[k] = runl; runl += h[k]; }
  }
  __syncthreads();
  if (tid < 64) posL[tid] = atomicAdd(&curB[c * 64u + tid], h[tid]);
  __syncthreads();

#pragma unroll
  for (int i = 0; i < 16; ++i) {
    if (rkd[i] != 0xFFFFFFFFu) {
      unsigned idx = lo + i * 256u + tid;
      unsigned dh = rkd[i] >> 12;
      unsigned slot = sb[dh] + (rkd[i] & 0xFFFu);
      buf[slot] = recA[idx];
      dh6[slot] = (unsigned char)dh;
    }
  }
  __syncthreads();

  for (unsigned i = tid; i < cnt; i += 256) {
    unsigned k = dh6[i];
    unsigned pos = posL[k] + i - sb[k];
    rec[pos] = buf[i];
  }
}

// shfl-based exclusive scan helper (256 threads, packed 16+16 fields)
__device__ __forceinline__ unsigned block_excl_scan_packed(
    unsigned packed, unsigned* wsum, int tid) {
  unsigned v = packed;
#pragma unroll
  for (int off = 1; off < 64; off <<= 1) {
    unsigned t = __shfl_up(v, off, 64);
    if ((tid & 63) >= off) v += t;
  }
  if ((tid & 63) == 63) wsum[tid >> 6] = v;
  __syncthreads();
  const int wid = tid >> 6;
  unsigned wpre = 0;
#pragma unroll
  for (int wmid = 0; wmid < 4; ++wmid)
    if (wmid < wid) wpre += wsum[wmid];
  return v + wpre - packed;            // exclusive
}

// ---------------------------------------------------------------------------
// Conv1 (dual counting sort, shfl scan) -> z2, r2   [round-14 version]
// ---------------------------------------------------------------------------
__global__ __launch_bounds__(256) void k_conv1s(
    const uint2* __restrict__ rec, const unsigned* __restrict__ base,
    const float* __restrict__ x,
    const float* __restrict__ W1_rel, const float* __restrict__ b1,
    const float* __restrict__ W1_root,
    const float* __restrict__ W2_rel, const float* __restrict__ b2,
    const float* __restrict__ W2_root,
    float* __restrict__ z2, float* __restrict__ r2, unsigned bkoff) {
  __shared__ float buf[CH * STW];
  __shared__ uint2 prm[CH];
  __shared__ unsigned hd[256];
  __shared__ unsigned hs[256];
  __shared__ unsigned sc[256];
  __shared__ unsigned wsum[4];
  const int tid = threadIdx.x;
  const unsigned bk = blockIdx.x + bkoff;
  const unsigned r0 = base[bk], r1 = base[bk + 1];

  float a[16];
#pragma unroll
  for (int i = 0; i < 16; ++i) a[i] = 0.f;

  for (unsigned c0 = r0; c0 < r1; c0 += CH) {
    const unsigned validCnt = min((unsigned)CH, r1 - c0);
    hd[tid] = 0u; hs[tid] = 0u;
    __syncthreads();

    const unsigned i0 = c0 + tid;
    const unsigned i1 = c0 + 256u + tid;
    const bool qa = i0 < r1;
    const bool qb = i1 < r1;
    unsigned srcA = 0, srcB = 0, la = 0, lb = 0, sa = 0, sb2 = 0;
    unsigned wa = 0, wb = 0, rkda = 0, rkdb = 0, rksa = 0, rksb = 0;
    if (qa) {
      uint2 ra = rec[i0];
      srcA = ra.x & SRCM; la = ra.x >> 21; sa = srcA >> 13; wa = ra.y;
    }
    if (qb) {
      uint2 rb = rec[i1];
      srcB = rb.x & SRCM; lb = rb.x >> 21; sb2 = srcB >> 13; wb = rb.y;
    }
    if (qa) { rkda = atomicAdd(&hd[la], 1u); rksa = atomicAdd(&hs[sa], 1u); }
    if (qb) { rkdb = atomicAdd(&hd[lb], 1u); rksb = atomicAdd(&hs[sb2], 1u); }
    __syncthreads();

    const unsigned cd = hd[tid];
    const unsigned packed = cd | (hs[tid] << 16);
    const unsigned exclP = block_excl_scan_packed(packed, wsum, tid);
    const unsigned myoff = exclP & 0xffffu;
    sc[tid] = exclP;
    __syncthreads();

    if (qa) {
      unsigned dslot = (sc[la] & 0xffffu) + rkda;
      unsigned spos  = (sc[sa] >> 16) + rksa;
      prm[spos] = make_uint2(srcA | (dslot << 21), wa);
    }
    if (qb) {
      unsigned dslot = (sc[lb] & 0xffffu) + rkdb;
      unsigned spos  = (sc[sb2] >> 16) + rksb;
      prm[spos] = make_uint2(srcB | (dslot << 21), wb);
    }
    __syncthreads();

    {
      const bool ga = tid < validCnt;
      const bool gb = tid + 256u < validCnt;
      uint2 pa, pb;
      float4 xa0, xa1, xa2, xa3, xb0, xb1, xb2, xb3;
      if (ga) {
        pa = prm[tid];
        const float4* xp = reinterpret_cast<const float4*>(x + (size_t)(pa.x & SRCM) * 16);
        xa0 = xp[0]; xa1 = xp[1]; xa2 = xp[2]; xa3 = xp[3];
      }
      if (gb) {
        pb = prm[tid + 256];
        const float4* xp = reinterpret_cast<const float4*>(x + (size_t)(pb.x & SRCM) * 16);
        xb0 = xp[0]; xb1 = xp[1]; xb2 = xp[2]; xb3 = xp[3];
      }
      if (ga) {
        float w = __uint_as_float(pa.y);
        float* bp = buf + (size_t)(pa.x >> 21) * STW;
        reinterpret_cast<float4*>(bp)[0] = make_float4(xa0.x*w, xa0.y*w, xa0.z*w, xa0.w*w);
        reinterpret_cast<float4*>(bp)[1] = make_float4(xa1.x*w, xa1.y*w, xa1.z*w, xa1.w*w);
        reinterpret_cast<float4*>(bp)[2] = make_float4(xa2.x*w, xa2.y*w, xa2.z*w, xa2.w*w);
        reinterpret_cast<float4*>(bp)[3] = make_float4(xa3.x*w, xa3.y*w, xa3.z*w, xa3.w*w);
      }
      if (gb) {
        float w = __uint_as_float(pb.y);
        float* bp = buf + (size_t)(pb.x >> 21) * STW;
        reinterpret_cast<float4*>(bp)[0] = make_float4(xb0.x*w, xb0.y*w, xb0.z*w, xb0.w*w);
        reinterpret_cast<float4*>(bp)[1] = make_float4(xb1.x*w, xb1.y*w, xb1.z*w, xb1.w*w);
        reinterpret_cast<float4*>(bp)[2] = make_float4(xb2.x*w, xb2.y*w, xb2.z*w, xb2.w*w);
        reinterpret_cast<float4*>(bp)[3] = make_float4(xb3.x*w, xb3.y*w, xb3.z*w, xb3.w*w);
      }
    }
    __syncthreads();

    for (unsigned k = 0; k < cd; ++k) {
      const float* bp = buf + (size_t)(myoff + k) * STW;
      float4 m0 = reinterpret_cast<const float4*>(bp)[0];
      float4 m1 = reinterpret_cast<const float4*>(bp)[1];
      float4 m2 = reinterpret_cast<const float4*>(bp)[2];
      float4 m3 = reinterpret_cast<const float4*>(bp)[3];
      a[0]  += m0.x; a[1]  += m0.y; a[2]  += m0.z; a[3]  += m0.w;
      a[4]  += m1.x; a[5]  += m1.y; a[6]  += m1.z; a[7]  += m1.w;
      a[8]  += m2.x; a[9]  += m2.y; a[10] += m2.z; a[11] += m2.w;
      a[12] += m3.x; a[13] += m3.y; a[14] += m3.z; a[15] += m3.w;
    }
    __syncthreads();
  }

  size_t n = (size_t)bk * RB + tid;
  float xv[16];
  {
    const float4* xp = reinterpret_cast<const float4*>(x + n * 16);
#pragma unroll
    for (int q = 0; q < 4; ++q) {
      float4 t2 = xp[q];
      xv[4*q+0] = t2.x; xv[4*q+1] = t2.y; xv[4*q+2] = t2.z; xv[4*q+3] = t2.w;
    }
  }
  float h[DH];
#pragma unroll
  for (int j = 0; j < DH; ++j) h[j] = b1[j];
#pragma unroll
  for (int i = 0; i < DIN; ++i) {
    float ai = a[i], xi = xv[i];
#pragma unroll
    for (int j = 0; j < DH; ++j)
      h[j] = fmaf(ai, W1_rel[i * DH + j], fmaf(xi, W1_root[i * DH + j], h[j]));
  }
#pragma unroll
  for (int j = 0; j < DH; ++j) h[j] = fmaxf(h[j], 0.f);
  float z[4] = {0.f, 0.f, 0.f, 0.f};
  float r[4] = {b2[0], b2[1], b2[2], b2[3]};
#pragma unroll
  for (int j = 0; j < DH; ++j) {
    float hj = h[j];
#pragma unroll
    for (int k = 0; k < 4; ++k) {
      z[k] = fmaf(hj, W2_rel[j * 4 + k], z[k]);
      r[k] = fmaf(hj, W2_root[j * 4 + k], r[k]);
    }
  }
  *reinterpret_cast<float4*>(z2 + n * 4) = make_float4(z[0], z[1], z[2], z[3]);
  *reinterpret_cast<float4*>(r2 + n * 4) = make_float4(r[0], r[1], r[2], r[3]);
}

// ---------------------------------------------------------------------------
// Conv2 (dual counting sort, shfl scan, 16B rows)   [round-14 version]
// ---------------------------------------------------------------------------
__global__ __launch_bounds__(256) void k_conv2s(
    const uint2* __restrict__ rec, const unsigned* __restrict__ base,
    const float* __restrict__ z2, const float* __restrict__ r2,
    float* __restrict__ embeds, unsigned bkoff) {
  __shared__ float buf[CH * ST2];
  __shared__ uint2 prm[CH];
  __shared__ unsigned hd[256];
  __shared__ unsigned hs[256];
  __shared__ unsigned sc[256];
  __shared__ unsigned wsum[4];
  const int tid = threadIdx.x;
  const unsigned bk = blockIdx.x + bkoff;
  const unsigned r0 = base[bk], r1 = base[bk + 1];

  float4 a = make_float4(0.f, 0.f, 0.f, 0.f);

  for (unsigned c0 = r0; c0 < r1; c0 += CH) {
    const unsigned validCnt = min((unsigned)CH, r1 - c0);
    hd[tid] = 0u; hs[tid] = 0u;
    __syncthreads();

    const unsigned i0 = c0 + tid;
    const unsigned i1 = c0 + 256u + tid;
    const bool qa = i0 < r1;
    const bool qb = i1 < r1;
    unsigned srcA = 0, srcB = 0, la = 0, lb = 0, sa = 0, sb2 = 0;
    unsigned wa = 0, wb = 0, rkda = 0, rkdb = 0, rksa = 0, rksb = 0;
    if (qa) {
      uint2 ra = rec[i0];
      srcA = ra.x & SRCM; la = ra.x >> 21; sa = srcA >> 13; wa = ra.y;
    }
    if (qb) {
      uint2 rb = rec[i1];
      srcB = rb.x & SRCM; lb = rb.x >> 21; sb2 = srcB >> 13; wb = rb.y;
    }
    if (qa) { rkda = atomicAdd(&hd[la], 1u); rksa = atomicAdd(&hs[sa], 1u); }
    if (qb) { rkdb = atomicAdd(&hd[lb], 1u); rksb = atomicAdd(&hs[sb2], 1u); }
    __syncthreads();

    const unsigned cd = hd[tid];
    const unsigned packed = cd | (hs[tid] << 16);
    const unsigned exclP = block_excl_scan_packed(packed, wsum, tid);
    const unsigned myoff = exclP & 0xffffu;
    sc[tid] = exclP;
    __syncthreads();

    if (qa) {
      unsigned dslot = (sc[la] & 0xffffu) + rkda;
      unsigned spos  = (sc[sa] >> 16) + rksa;
      prm[spos] = make_uint2(srcA | (dslot << 21), wa);
    }
    if (qb) {
      unsigned dslot = (sc[lb] & 0xffffu) + rkdb;
      unsigned spos  = (sc[sb2] >> 16) + rksb;
      prm[spos] = make_uint2(srcB | (dslot << 21), wb);
    }
    __syncthreads();

    {
      const bool ga = tid < validCnt;
      const bool gb = tid + 256u < validCnt;
      uint2 pa, pb;
      float4 za, zb;
      if (ga) {
        pa = prm[tid];
        za = *reinterpret_cast<const float4*>(z2 + (size_t)(pa.x & SRCM) * 4);
      }
      if (gb) {
        pb = prm[tid + 256];
        zb = *reinterpret_cast<const float4*>(z2 + (size_t)(pb.x & SRCM) * 4);
      }
      if (ga) {
        float w = __uint_as_float(pa.y);
        *reinterpret_cast<float4*>(buf + (size_t)(pa.x >> 21) * ST2) =
            make_float4(za.x*w, za.y*w, za.z*w, za.w*w);
      }
      if (gb) {
        float w = __uint_as_float(pb.y);
        *reinterpret_cast<float4*>(buf + (size_t)(pb.x >> 21) * ST2) =
            make_float4(zb.x*w, zb.y*w, zb.z*w, zb.w*w);
      }
    }
    __syncthreads();

    for (unsigned k = 0; k < cd; ++k) {
      float4 m = *reinterpret_cast<const float4*>(buf + (size_t)(myoff + k) * ST2);
      a.x += m.x; a.y += m.y; a.z += m.z; a.w += m.w;
    }
    __syncthreads();
  }

  size_t n = (size_t)bk * RB + tid;
  const float4 rr = *reinterpret_cast<const float4*>(r2 + n * 4);
  float4 o;
  o.x = fmaxf(a.x + rr.x, 0.f);
  o.y = fmaxf(a.y + rr.y, 0.f);
  o.z = fmaxf(a.z + rr.z, 0.f);
  o.w = fmaxf(a.w + rr.w, 0.f);
  *reinterpret_cast<float4*>(embeds + n * 4) = o;
}

// ---------------------------------------------------------------------------
// Final MLP (round-15 version)
// ---------------------------------------------------------------------------
__global__ __launch_bounds__(256, 2) void k_final(
    const float* __restrict__ embeds, const float* __restrict__ gfeat,
    const float* __restrict__ Wg1, const float* __restrict__ bg1,
    const float* __restrict__ Wg2, const float* __restrict__ bg2,
    const float* __restrict__ Wg3, const float* __restrict__ bg3,
    const float* __restrict__ Wo1, const float* __restrict__ bo1,
    const float* __restrict__ Wo2, const float* __restrict__ bo2,
    const float* __restrict__ Wo3, const float* __restrict__ bo3,
    float* __restrict__ out) {
  __shared__ float svec[TBF * 232];
  __shared__ float sbuf1[TBF * 128];
  float* sbuf2 = svec;

  const int tid = threadIdx.x;
  const int b0  = blockIdx.x * TBF;

  {
    const float4* src = reinterpret_cast<const float4*>(embeds + (size_t)b0 * 216);
    for (int f4i = tid; f4i < TBF * 54; f4i += 256) {
      int b = f4i / 54;
      int k4 = f4i - b * 54;
      *reinterpret_cast<float4*>(svec + b * 232 + k4 * 4) = src[f4i];
    }
  }
  if (tid < TBF) {
    const float* gf = gfeat + (size_t)(b0 + tid) * GLOBF;
    float gin[16];
#pragma unroll
    for (int i = 0; i < 16; ++i) gin[i] = gf[i];
    float g1[8];
#pragma unroll
    for (int j = 0; j < 8; ++j) {
      float acc = bg1[j];
#pragma unroll
      for (int i = 0; i < 16; ++i) acc = fmaf(gin[i], Wg1[i * 8 + j], acc);
      g1[j] = fmaxf(acc, 0.f);
    }
    float g2[8];
#pragma unroll
    for (int j = 0; j < 8; ++j) {
      float acc = bg2[j];
#pragma unroll
      for (int i = 0; i < 8; ++i) acc = fmaf(g1[i], Wg2[i * 8 + j], acc);
      g2[j] = fmaxf(acc, 0.f);
    }
#pragma unroll
    for (int j = 0; j < 16; ++j) {
      float acc = bg3[j];
#pragma unroll
      for (int i = 0; i < 8; ++i) acc = fmaf(g2[i], Wg3[i * 16 + j], acc);
      svec[tid * 232 + 216 + j] = fmaxf(acc, 0.f);
    }
  }
  __syncthreads();

  const int c0 = (tid & 31) * 4;
  const int rb = (tid >> 5) * 4;

  {
    const float* Wp = Wo1 + c0;
    float4 w0 = *reinterpret_cast<const float4*>(Wp + 0 * 128);
    float4 w1 = *reinterpret_cast<const float4*>(Wp + 1 * 128);
    float4 w2 = *reinterpret_cast<const float4*>(Wp + 2 * 128);
    float4 w3 = *reinterpret_cast<const float4*>(Wp + 3 * 128);
    float acc[4][4];
#pragma unroll
    for (int r = 0; r < 4; ++r)
#pragma unroll
      for (int c = 0; c < 4; ++c) acc[r][c] = 0.f;
    for (int i4 = 0; i4 < 58; ++i4) {
      float4 n0, n1, n2, n3;
      if (i4 < 57) {
        const float* Np = Wp + (size_t)(i4 * 4 + 4) * 128;
        n0 = *reinterpret_cast<const float4*>(Np + 0 * 128);
        n1 = *reinterpret_cast<const float4*>(Np + 1 * 128);
        n2 = *reinterpret_cast<const float4*>(Np + 2 * 128);
        n3 = *reinterpret_cast<const float4*>(Np + 3 * 128);
      }
#pragma unroll
      for (int r = 0; r < 4; ++r) {
        const float4 s = *reinterpret_cast<const float4*>(svec + (rb+r)*232 + i4*4);
        acc[r][0] = fmaf(s.x, w0.x, fmaf(s.y, w1.x, fmaf(s.z, w2.x, fmaf(s.w, w3.x, acc[r][0]))));
        acc[r][1] = fmaf(s.x, w0.y, fmaf(s.y, w1.y, fmaf(s.z, w2.y, fmaf(s.w, w3.y, acc[r][1]))));
        acc[r][2] = fmaf(s.x, w0.z, fmaf(s.y, w1.z, fmaf(s.z, w2.z, fmaf(s.w, w3.z, acc[r][2]))));
        acc[r][3] = fmaf(s.x, w0.w, fmaf(s.y, w1.w, fmaf(s.z, w2.w, fmaf(s.w, w3.w, acc[r][3]))));
      }
      w0 = n0; w1 = n1; w2 = n2; w3 = n3;
    }
    const float4 bv = *reinterpret_cast<const float4*>(bo1 + c0);
#pragma unroll
    for (int r = 0; r < 4; ++r) {
      float4 o;
      o.x = fmaxf(acc[r][0] + bv.x, 0.f);
      o.y = fmaxf(acc[r][1] + bv.y, 0.f);
      o.z = fmaxf(acc[r][2] + bv.z, 0.f);
      o.w = fmaxf(acc[r][3] + bv.w, 0.f);
      *reinterpret_cast<float4*>(sbuf1 + (rb + r) * 128 + c0) = o;
    }
  }
  __syncthreads();

  {
    const float* Wp = Wo2 + c0;
    float4 w0 = *reinterpret_cast<const float4*>(Wp + 0 * 128);
    float4 w1 = *reinterpret_cast<const float4*>(Wp + 1 * 128);
    float4 w2 = *reinterpret_cast<const float4*>(Wp + 2 * 128);
    float4 w3 = *reinterpret_cast<const float4*>(Wp + 3 * 128);
    float acc[4][4];
#pragma unroll
    for (int r = 0; r < 4; ++r)
#pragma unroll
      for (int c = 0; c < 4; ++c) acc[r][c] = 0.f;
    for (int i4 = 0; i4 < 32; ++i4) {
      float4 n0, n1, n2, n3;
      if (i4 < 31) {
        const float* Np = Wp + (size_t)(i4 * 4 + 4) * 128;
        n0 = *reinterpret_cast<const float4*>(Np + 0 * 128);
        n1 = *reinterpret_cast<const float4*>(Np + 1 * 128);
        n2 = *reinterpret_cast<const float4*>(Np + 2 * 128);
        n3 = *reinterpret_cast<const float4*>(Np + 3 * 128);
      }
#pragma unroll
      for (int r = 0; r < 4; ++r) {
        const float4 s = *reinterpret_cast<const float4*>(sbuf1 + (rb+r)*128 + i4*4);
        acc[r][0] = fmaf(s.x, w0.x, fmaf(s.y, w1.x, fmaf(s.z, w2.x, fmaf(s.w, w3.x, acc[r][0]))));
        acc[r][1] = fmaf(s.x, w0.y, fmaf(s.y, w1.y, fmaf(s.z, w2.y, fmaf(s.w, w3.y, acc[r][1]))));
        acc[r][2] = fmaf(s.x, w0.z, fmaf(s.y, w1.z, fmaf(s.z, w2.z, fmaf(s.w, w3.z, acc[r][2]))));
        acc[r][3] = fmaf(s.x, w0.w, fmaf(s.y, w1.w, fmaf(s.z, w2.w, fmaf(s.w, w3.w, acc[r][3]))));
      }
      w0 = n0; w1 = n1; w2 = n2; w3 = n3;
    }
    const float4 bv = *reinterpret_cast<const float4*>(bo2 + c0);
#pragma unroll
    for (int r = 0; r < 4; ++r) {
      float4 o;
      o.x = fmaxf(acc[r][0] + bv.x, 0.f);
      o.y = fmaxf(acc[r][1] + bv.y, 0.f);
      o.z = fmaxf(acc[r][2] + bv.z, 0.f);
      o.w = fmaxf(acc[r][3] + bv.w, 0.f);
      *reinterpret_cast<float4*>(sbuf2 + (rb + r) * 128 + c0) = o;
    }
  }
  __syncthreads();

  {
    const int c2 = (tid & 31) * 2;
    const float* Wp = Wo3 + c2;
    float2 w0 = *reinterpret_cast<const float2*>(Wp + 0 * 64);
    float2 w1 = *reinterpret_cast<const float2*>(Wp + 1 * 64);
    float2 w2 = *reinterpret_cast<const float2*>(Wp + 2 * 64);
    float2 w3 = *reinterpret_cast<const float2*>(Wp + 3 * 64);
    float acc[4][2];
#pragma unroll
    for (int r = 0; r < 4; ++r) { acc[r][0] = 0.f; acc[r][1] = 0.f; }
    for (int i4 = 0; i4 < 32; ++i4) {
      float2 n0, n1, n2, n3;
      if (i4 < 31) {
        const float* Np = Wp + (size_t)(i4 * 4 + 4) * 64;
        n0 = *reinterpret_cast<const float2*>(Np + 0 * 64);
        n1 = *reinterpret_cast<const float2*>(Np + 1 * 64);
        n2 = *reinterpret_cast<const float2*>(Np + 2 * 64);
        n3 = *reinterpret_cast<const float2*>(Np + 3 * 64);
      }
#pragma unroll
      for (int r = 0; r < 4; ++r) {
        const float4 s = *reinterpret_cast<const float4*>(sbuf2 + (rb+r)*128 + i4*4);
        acc[r][0] = fmaf(s.x, w0.x, fmaf(s.y, w1.x, fmaf(s.z, w2.x, fmaf(s.w, w3.x, acc[r][0]))));
        acc[r][1] = fmaf(s.x, w0.y, fmaf(s.y, w1.y, fmaf(s.z, w2.y, fmaf(s.w, w3.y, acc[r][1]))));
      }
      w0 = n0; w1 = n1; w2 = n2; w3 = n3;
    }
    const float2 bv = *reinterpret_cast<const float2*>(bo3 + c2);
#pragma unroll
    for (int r = 0; r < 4; ++r) {
      float2 o;
      o.x = acc[r][0] + bv.x;
      o.y = acc[r][1] + bv.y;
      *reinterpret_cast<float2*>(out + (size_t)(b0 + rb + r) * 64 + c2) = o;
    }
  }
}

// ---------------------------------------------------------------------------
extern "C" void kernel_launch(void* const* d_in, const int* in_sizes, int n_in,
                              void* d_out, int out_size, void* d_ws, size_t ws_size,
                              hipStream_t stream) {
  const float* x      = (const float*)d_in[0];
  const int*   ei     = (const int*)d_in[1];
  const float* ea     = (const float*)d_in[2];
  const float* gfeat  = (const float*)d_in[3];
  const float* W1_rel = (const float*)d_in[5];
  const float* b1     = (const float*)d_in[6];
  const float* W1_root= (const float*)d_in[7];
  const float* W2_rel = (const float*)d_in[8];
  const float* b2     = (const float*)d_in[9];
  const float* W2_root= (const float*)d_in[10];
  const float* Wg1 = (const float*)d_in[11];
  const float* bg1 = (const float*)d_in[12];
  const float* Wg2 = (const float*)d_in[13];
  const float* bg2 = (const float*)d_in[14];
  const float* Wg3 = (const float*)d_in[15];
  const float* bg3 = (const float*)d_in[16];
  const float* Wo1 = (const float*)d_in[17];
  const float* bo1 = (const float*)d_in[18];
  const float* Wo2 = (const float*)d_in[19];
  const float* bo2 = (const float*)d_in[20];
  const float* Wo3 = (const float*)d_in[21];
  const float* bo3 = (const float*)d_in[22];
  float* outp = (float*)d_out;

  // workspace (~166 MB)
  uint2*    rec    = (uint2*)d_ws;                         // NE*8B
  uint2*    recA   = rec + NE;                             // NE*8B
  unsigned char* dhiA = (unsigned char*)(recA + NE);       // NE*1B
  float*    z2     = (float*)(dhiA + NE);                  // NN*4 f
  float*    r2     = z2 + (size_t)NN * 4;                  // NN*4 f
  float*    embeds = r2 + (size_t)NN * 4;                  // NN*4 f
  unsigned* hist   = (unsigned*)(embeds + (size_t)NN * 4); // NBK
  unsigned* base   = hist + NBK;                           // NBK+1
  unsigned* cursorB= base + NBK + 1;                       // NBK
  unsigned* curA   = cursorB + NBK;                        // NCL

  hipMemsetAsync(hist, 0, NBK * sizeof(unsigned), stream);
  k_histl <<<HB, 256, 0, stream>>>(ei, hist);
  k_scan2 <<<1, 1024, 0, stream>>>(hist, base, cursorB, curA);
  k_placeA<<<NBA, 256, 0, stream>>>(ei, ea, curA, recA, dhiA);
  k_placeB<<<NCL * CPB, 256, 0, stream>>>(recA, dhiA, base, cursorB, rec);
  for (unsigned q = 0; q < 4; ++q)
    k_conv1s<<<QBK, 256, 0, stream>>>(rec, base, x, W1_rel, b1, W1_root,
                                      W2_rel, b2, W2_root, z2, r2, q * QBK);
  for (unsigned q = 0; q < 4; ++q)
    k_conv2s<<<QBK, 256, 0, stream>>>(rec, base, z2, r2, embeds, q * QBK);
  k_final<<<BD / TBF, 256, 0, stream>>>(embeds, gfeat,
                                        Wg1, bg1, Wg2, bg2, Wg3, bg3,
                                        Wo1, bo1, Wo2, bo2, Wo3, bo3, outp);
}

// Round 18
// 494.337 us; speedup vs baseline: 1.6648x; 1.0097x over previous
//
#include <hip/hip_runtime.h>

// Problem constants
#define BD   32768
#define NPG  54
#define NN   (BD * NPG)          // 1,769,472 nodes
#define NE   (BD * 144)          // 4,718,592 edges
#define DIN  16
#define DH   32
#define GLOBF 16
#define TBF  32                  // boards per final block
#define RB   256                 // nodes per dst bucket
#define NBK  (NN / RB)           // 6912 buckets
#define QBK  (NBK / 4)
#define SRCM 0x1FFFFFu           // 21-bit src mask
#define CH   512                 // conv sort-chunk
#define STW  18                  // conv1 sort-row stride (floats): 72B, b64-aligned, 16 banks -> 2-way
#define ST2  6                   // conv2 sort-row stride (floats): 24B, b64-aligned, 16 banks -> 2-way
#define HB   256                 // hist blocks
#define EB   4096                // edges per place block
#define NBA  (NE / EB)           // 1152
#define NCL  108                 // classes = d>>14 (64 buckets each)
#define CPB  12                  // placeB chunks per class

// ---------------------------------------------------------------------------
// Pass 1: dst-bucket histogram (LDS-staged)
// ---------------------------------------------------------------------------
__global__ __launch_bounds__(256) void k_histl(const int* __restrict__ ei,
                                               unsigned* __restrict__ hist) {
  __shared__ unsigned h[NBK];                            // 27648 B
  const int tid = threadIdx.x;
  for (int i = tid; i < NBK; i += 256) h[i] = 0u;
  __syncthreads();
  const unsigned base = blockIdx.x * (NE / HB);
  for (unsigned i = tid; i < NE / HB; i += 256u) {
    unsigned d = (unsigned)ei[NE + base + i];
    atomicAdd(&h[d >> 8], 1u);
  }
  __syncthreads();
  for (int i = tid; i < NBK; i += 256)
    if (h[i]) atomicAdd(&hist[i], h[i]);
}

// ---------------------------------------------------------------------------
// Pass 2: exclusive scan; also inits class cursors for placeA
// ---------------------------------------------------------------------------
__global__ __launch_bounds__(1024) void k_scan2(const unsigned* __restrict__ hist,
                                                unsigned* __restrict__ base,
                                                unsigned* __restrict__ cursorB,
                                                unsigned* __restrict__ curA) {
  __shared__ unsigned s[1024];
  const int tid = threadIdx.x;
  unsigned loc[7]; unsigned run = 0;
#pragma unroll
  for (int j = 0; j < 7; ++j) {
    int idx = tid * 7 + j;
    unsigned v = (idx < NBK) ? hist[idx] : 0u;
    loc[j] = run; run += v;
  }
  s[tid] = run; __syncthreads();
  for (int off = 1; off < 1024; off <<= 1) {
    unsigned t = (tid >= off) ? s[tid - off] : 0u;
    __syncthreads(); s[tid] += t; __syncthreads();
  }
  unsigned cb = tid ? s[tid - 1] : 0u;
#pragma unroll
  for (int j = 0; j < 7; ++j) {
    int idx = tid * 7 + j;
    if (idx < NBK) {
      unsigned b = cb + loc[j];
      base[idx] = b; cursorB[idx] = b;
      if ((idx & 63) == 0) curA[idx >> 6] = b;
    }
  }
  if (tid == 1023) base[NBK] = s[1023];                  // = NE
}

// ---------------------------------------------------------------------------
// placeA: LDS counting sort of 4096 edges by class (d>>14), run-claim flush
// ---------------------------------------------------------------------------
__global__ __launch_bounds__(256) void k_placeA(
    const int* __restrict__ ei, const float* __restrict__ ea,
    unsigned* __restrict__ curA, uint2* __restrict__ recA,
    unsigned char* __restrict__ dhiA) {
  __shared__ uint2 buf[EB];                              // 32768 B
  __shared__ unsigned char cls8[EB];                     // 4096 B
  __shared__ unsigned char dh6[EB];                      // 4096 B
  __shared__ unsigned h[NCL];
  __shared__ unsigned sb[NCL];
  __shared__ unsigned posL[NCL];
  const int tid = threadIdx.x;
  const unsigned eb = blockIdx.x * (unsigned)EB;

  for (int k = tid; k < NCL; k += 256) h[k] = 0u;
  __syncthreads();

  unsigned rkcls[16];                                    // rank(12b) | class<<12
#pragma unroll
  for (int i = 0; i < 16; ++i) {
    unsigned e = eb + i * 256u + tid;
    unsigned d = (unsigned)ei[NE + e];
    unsigned c = d >> 14;
    unsigned rk = atomicAdd(&h[c], 1u);
    rkcls[i] = rk | (c << 12);
  }
  __syncthreads();
  if (tid == 0) {
    unsigned runl = 0;
    for (int k = 0; k < NCL; ++k) { sb[k] = runl; runl += h[k]; }
  }
  __syncthreads();
  if (tid < NCL) posL[tid] = atomicAdd(&curA[tid], h[tid]);
  __syncthreads();

#pragma unroll
  for (int i = 0; i < 16; ++i) {
    unsigned e = eb + i * 256u + tid;
    unsigned sv = (unsigned)ei[e];
    unsigned d  = (unsigned)ei[NE + e];
    float    w  = ea[e];
    unsigned c  = rkcls[i] >> 12;
    unsigned slot = sb[c] + (rkcls[i] & 0xFFFu);
    buf[slot]  = make_uint2(sv | ((d & 255u) << 21), __float_as_uint(w));
    cls8[slot] = (unsigned char)c;
    dh6[slot]  = (unsigned char)((d >> 8) & 63u);
  }
  __syncthreads();

  for (int i = tid; i < EB; i += 256) {
    unsigned c = cls8[i];
    unsigned pos = posL[c] + (unsigned)i - sb[c];
    recA[pos] = buf[i];
    dhiA[pos] = dh6[i];
  }
}

// ---------------------------------------------------------------------------
// placeB: within class, sort 4096-record chunk by bucket-in-class, run-claims
// ---------------------------------------------------------------------------
__global__ __launch_bounds__(256) void k_placeB(
    const uint2* __restrict__ recA, const unsigned char* __restrict__ dhiA,
    const unsigned* __restrict__ base, unsigned* __restrict__ curB,
    uint2* __restrict__ rec) {
  __shared__ uint2 buf[EB];                              // 32768 B
  __shared__ unsigned char dh6[EB];                      // 4096 B
  __shared__ unsigned h[64];
  __shared__ unsigned sb[64];
  __shared__ unsigned posL[64];
  const int tid = threadIdx.x;
  const unsigned c = blockIdx.x / CPB;
  const unsigned j = blockIdx.x % CPB;
  const unsigned clsLo = base[c * 64];
  const unsigned clsHi = base[c * 64 + 64];
  const unsigned lo = clsLo + j * (unsigned)EB;
  if (lo >= clsHi) return;
  const unsigned hi = min(lo + (unsigned)EB, clsHi);
  const unsigned cnt = hi - lo;

  if (tid < 64) h[tid] = 0u;
  __syncthreads();

  unsigned rkd[16];
#pragma unroll
  for (int i = 0; i < 16; ++i) {
    unsigned idx = lo + i * 256u + tid;
    rkd[i] = 0xFFFFFFFFu;
    if (idx < hi) {
      unsigned dh = dhiA[idx];
      unsigned rk = atomicAdd(&h[dh], 1u);
      rkd[i] = rk | (dh << 12);
    }
  }
  __syncthreads();
  if (tid == 0) {
    unsigned runl = 0;
    for (int k = 0; k < 64; ++k) { sb[k] = runl; runl += h[k]; }
  }
  __syncthreads();
  if (tid < 64) posL[tid] = atomicAdd(&curB[c * 64u + tid], h[tid]);
  __syncthreads();

#pragma unroll
  for (int i = 0; i < 16; ++i) {
    if (rkd[i] != 0xFFFFFFFFu) {
      unsigned idx = lo + i * 256u + tid;
      unsigned dh = rkd[i] >> 12;
      unsigned slot = sb[dh] + (rkd[i] & 0xFFFu);
      buf[slot] = recA[idx];
      dh6[slot] = (unsigned char)dh;
    }
  }
  __syncthreads();

  for (unsigned i = tid; i < cnt; i += 256) {
    unsigned k = dh6[i];
    unsigned pos = posL[k] + i - sb[k];
    rec[pos] = buf[i];
  }
}

// shfl-based exclusive scan helper (256 threads, packed 16+16 fields)
__device__ __forceinline__ unsigned block_excl_scan_packed(
    unsigned packed, unsigned* wsum, int tid) {
  unsigned v = packed;
#pragma unroll
  for (int off = 1; off < 64; off <<= 1) {
    unsigned t = __shfl_up(v, off, 64);
    if ((tid & 63) >= off) v += t;
  }
  if ((tid & 63) == 63) wsum[tid >> 6] = v;
  __syncthreads();
  const int wid = tid >> 6;
  unsigned wpre = 0;
#pragma unroll
  for (int wmid = 0; wmid < 4; ++wmid)
    if (wmid < wid) wpre += wsum[wmid];
  return v + wpre - packed;            // exclusive
}

// ---------------------------------------------------------------------------
// Conv1 (dual counting sort; STW=18 float2 rows -> 2-way banks) -> z2, r2
// ---------------------------------------------------------------------------
__global__ __launch_bounds__(256) void k_conv1s(
    const uint2* __restrict__ rec, const unsigned* __restrict__ base,
    const float* __restrict__ x,
    const float* __restrict__ W1_rel, const float* __restrict__ b1,
    const float* __restrict__ W1_root,
    const float* __restrict__ W2_rel, const float* __restrict__ b2,
    const float* __restrict__ W2_root,
    float* __restrict__ z2, float* __restrict__ r2, unsigned bkoff) {
  __shared__ float buf[CH * STW];        // 36864 B
  __shared__ uint2 prm[CH];              // 4096 B
  __shared__ unsigned hd[256];
  __shared__ unsigned hs[256];
  __shared__ unsigned sc[256];
  __shared__ unsigned wsum[4];
  const int tid = threadIdx.x;
  const unsigned bk = blockIdx.x + bkoff;
  const unsigned r0 = base[bk], r1 = base[bk + 1];

  float a[16];
#pragma unroll
  for (int i = 0; i < 16; ++i) a[i] = 0.f;

  for (unsigned c0 = r0; c0 < r1; c0 += CH) {
    const unsigned validCnt = min((unsigned)CH, r1 - c0);
    hd[tid] = 0u; hs[tid] = 0u;
    __syncthreads();

    const unsigned i0 = c0 + tid;
    const unsigned i1 = c0 + 256u + tid;
    const bool qa = i0 < r1;
    const bool qb = i1 < r1;
    unsigned srcA = 0, srcB = 0, la = 0, lb = 0, sa = 0, sb2 = 0;
    unsigned wa = 0, wb = 0, rkda = 0, rkdb = 0, rksa = 0, rksb = 0;
    if (qa) {
      uint2 ra = rec[i0];
      srcA = ra.x & SRCM; la = ra.x >> 21; sa = srcA >> 13; wa = ra.y;
    }
    if (qb) {
      uint2 rb = rec[i1];
      srcB = rb.x & SRCM; lb = rb.x >> 21; sb2 = srcB >> 13; wb = rb.y;
    }
    if (qa) { rkda = atomicAdd(&hd[la], 1u); rksa = atomicAdd(&hs[sa], 1u); }
    if (qb) { rkdb = atomicAdd(&hd[lb], 1u); rksb = atomicAdd(&hs[sb2], 1u); }
    __syncthreads();

    const unsigned cd = hd[tid];
    const unsigned packed = cd | (hs[tid] << 16);
    const unsigned exclP = block_excl_scan_packed(packed, wsum, tid);
    const unsigned myoff = exclP & 0xffffu;
    sc[tid] = exclP;
    __syncthreads();

    if (qa) {
      unsigned dslot = (sc[la] & 0xffffu) + rkda;
      unsigned spos  = (sc[sa] >> 16) + rksa;
      prm[spos] = make_uint2(srcA | (dslot << 21), wa);
    }
    if (qb) {
      unsigned dslot = (sc[lb] & 0xffffu) + rkdb;
      unsigned spos  = (sc[sb2] >> 16) + rksb;
      prm[spos] = make_uint2(srcB | (dslot << 21), wb);
    }
    __syncthreads();

    // gather phase in ascending-src order; scatter as 8x float2 (b64)
    {
      const bool ga = tid < validCnt;
      const bool gb = tid + 256u < validCnt;
      uint2 pa, pb;
      float4 xa0, xa1, xa2, xa3, xb0, xb1, xb2, xb3;
      if (ga) {
        pa = prm[tid];
        const float4* xp = reinterpret_cast<const float4*>(x + (size_t)(pa.x & SRCM) * 16);
        xa0 = xp[0]; xa1 = xp[1]; xa2 = xp[2]; xa3 = xp[3];
      }
      if (gb) {
        pb = prm[tid + 256];
        const float4* xp = reinterpret_cast<const float4*>(x + (size_t)(pb.x & SRCM) * 16);
        xb0 = xp[0]; xb1 = xp[1]; xb2 = xp[2]; xb3 = xp[3];
      }
      if (ga) {
        float w = __uint_as_float(pa.y);
        float2* bp2 = reinterpret_cast<float2*>(buf + (size_t)(pa.x >> 21) * STW);
        bp2[0] = make_float2(xa0.x*w, xa0.y*w);
        bp2[1] = make_float2(xa0.z*w, xa0.w*w);
        bp2[2] = make_float2(xa1.x*w, xa1.y*w);
        bp2[3] = make_float2(xa1.z*w, xa1.w*w);
        bp2[4] = make_float2(xa2.x*w, xa2.y*w);
        bp2[5] = make_float2(xa2.z*w, xa2.w*w);
        bp2[6] = make_float2(xa3.x*w, xa3.y*w);
        bp2[7] = make_float2(xa3.z*w, xa3.w*w);
      }
      if (gb) {
        float w = __uint_as_float(pb.y);
        float2* bp2 = reinterpret_cast<float2*>(buf + (size_t)(pb.x >> 21) * STW);
        bp2[0] = make_float2(xb0.x*w, xb0.y*w);
        bp2[1] = make_float2(xb0.z*w, xb0.w*w);
        bp2[2] = make_float2(xb1.x*w, xb1.y*w);
        bp2[3] = make_float2(xb1.z*w, xb1.w*w);
        bp2[4] = make_float2(xb2.x*w, xb2.y*w);
        bp2[5] = make_float2(xb2.z*w, xb2.w*w);
        bp2[6] = make_float2(xb3.x*w, xb3.y*w);
        bp2[7] = make_float2(xb3.z*w, xb3.w*w);
      }
    }
    __syncthreads();

    for (unsigned k = 0; k < cd; ++k) {
      const float2* bp2 = reinterpret_cast<const float2*>(buf + (size_t)(myoff + k) * STW);
      float2 m0 = bp2[0], m1 = bp2[1], m2 = bp2[2], m3 = bp2[3];
      float2 m4 = bp2[4], m5 = bp2[5], m6 = bp2[6], m7 = bp2[7];
      a[0]  += m0.x; a[1]  += m0.y; a[2]  += m1.x; a[3]  += m1.y;
      a[4]  += m2.x; a[5]  += m2.y; a[6]  += m3.x; a[7]  += m3.y;
      a[8]  += m4.x; a[9]  += m4.y; a[10] += m5.x; a[11] += m5.y;
      a[12] += m6.x; a[13] += m6.y; a[14] += m7.x; a[15] += m7.y;
    }
    __syncthreads();
  }

  size_t n = (size_t)bk * RB + tid;
  float xv[16];
  {
    const float4* xp = reinterpret_cast<const float4*>(x + n * 16);
#pragma unroll
    for (int q = 0; q < 4; ++q) {
      float4 t2 = xp[q];
      xv[4*q+0] = t2.x; xv[4*q+1] = t2.y; xv[4*q+2] = t2.z; xv[4*q+3] = t2.w;
    }
  }
  float h[DH];
#pragma unroll
  for (int j = 0; j < DH; ++j) h[j] = b1[j];
#pragma unroll
  for (int i = 0; i < DIN; ++i) {
    float ai = a[i], xi = xv[i];
#pragma unroll
    for (int j = 0; j < DH; ++j)
      h[j] = fmaf(ai, W1_rel[i * DH + j], fmaf(xi, W1_root[i * DH + j], h[j]));
  }
#pragma unroll
  for (int j = 0; j < DH; ++j) h[j] = fmaxf(h[j], 0.f);
  float z[4] = {0.f, 0.f, 0.f, 0.f};
  float r[4] = {b2[0], b2[1], b2[2], b2[3]};
#pragma unroll
  for (int j = 0; j < DH; ++j) {
    float hj = h[j];
#pragma unroll
    for (int k = 0; k < 4; ++k) {
      z[k] = fmaf(hj, W2_rel[j * 4 + k], z[k]);
      r[k] = fmaf(hj, W2_root[j * 4 + k], r[k]);
    }
  }
  *reinterpret_cast<float4*>(z2 + n * 4) = make_float4(z[0], z[1], z[2], z[3]);
  *reinterpret_cast<float4*>(r2 + n * 4) = make_float4(r[0], r[1], r[2], r[3]);
}

// ---------------------------------------------------------------------------
// Conv2 (dual counting sort; ST2=6 float2 rows -> 2-way banks)
// ---------------------------------------------------------------------------
__global__ __launch_bounds__(256) void k_conv2s(
    const uint2* __restrict__ rec, const unsigned* __restrict__ base,
    const float* __restrict__ z2, const float* __restrict__ r2,
    float* __restrict__ embeds, unsigned bkoff) {
  __shared__ float buf[CH * ST2];        // 12288 B
  __shared__ uint2 prm[CH];
  __shared__ unsigned hd[256];
  __shared__ unsigned hs[256];
  __shared__ unsigned sc[256];
  __shared__ unsigned wsum[4];
  const int tid = threadIdx.x;
  const unsigned bk = blockIdx.x + bkoff;
  const unsigned r0 = base[bk], r1 = base[bk + 1];

  float4 a = make_float4(0.f, 0.f, 0.f, 0.f);

  for (unsigned c0 = r0; c0 < r1; c0 += CH) {
    const unsigned validCnt = min((unsigned)CH, r1 - c0);
    hd[tid] = 0u; hs[tid] = 0u;
    __syncthreads();

    const unsigned i0 = c0 + tid;
    const unsigned i1 = c0 + 256u + tid;
    const bool qa = i0 < r1;
    const bool qb = i1 < r1;
    unsigned srcA = 0, srcB = 0, la = 0, lb = 0, sa = 0, sb2 = 0;
    unsigned wa = 0, wb = 0, rkda = 0, rkdb = 0, rksa = 0, rksb = 0;
    if (qa) {
      uint2 ra = rec[i0];
      srcA = ra.x & SRCM; la = ra.x >> 21; sa = srcA >> 13; wa = ra.y;
    }
    if (qb) {
      uint2 rb = rec[i1];
      srcB = rb.x & SRCM; lb = rb.x >> 21; sb2 = srcB >> 13; wb = rb.y;
    }
    if (qa) { rkda = atomicAdd(&hd[la], 1u); rksa = atomicAdd(&hs[sa], 1u); }
    if (qb) { rkdb = atomicAdd(&hd[lb], 1u); rksb = atomicAdd(&hs[sb2], 1u); }
    __syncthreads();

    const unsigned cd = hd[tid];
    const unsigned packed = cd | (hs[tid] << 16);
    const unsigned exclP = block_excl_scan_packed(packed, wsum, tid);
    const unsigned myoff = exclP & 0xffffu;
    sc[tid] = exclP;
    __syncthreads();

    if (qa) {
      unsigned dslot = (sc[la] & 0xffffu) + rkda;
      unsigned spos  = (sc[sa] >> 16) + rksa;
      prm[spos] = make_uint2(srcA | (dslot << 21), wa);
    }
    if (qb) {
      unsigned dslot = (sc[lb] & 0xffffu) + rkdb;
      unsigned spos  = (sc[sb2] >> 16) + rksb;
      prm[spos] = make_uint2(srcB | (dslot << 21), wb);
    }
    __syncthreads();

    {
      const bool ga = tid < validCnt;
      const bool gb = tid + 256u < validCnt;
      uint2 pa, pb;
      float4 za, zb;
      if (ga) {
        pa = prm[tid];
        za = *reinterpret_cast<const float4*>(z2 + (size_t)(pa.x & SRCM) * 4);
      }
      if (gb) {
        pb = prm[tid + 256];
        zb = *reinterpret_cast<const float4*>(z2 + (size_t)(pb.x & SRCM) * 4);
      }
      if (ga) {
        float w = __uint_as_float(pa.y);
        float2* bp2 = reinterpret_cast<float2*>(buf + (size_t)(pa.x >> 21) * ST2);
        bp2[0] = make_float2(za.x*w, za.y*w);
        bp2[1] = make_float2(za.z*w, za.w*w);
      }
      if (gb) {
        float w = __uint_as_float(pb.y);
        float2* bp2 = reinterpret_cast<float2*>(buf + (size_t)(pb.x >> 21) * ST2);
        bp2[0] = make_float2(zb.x*w, zb.y*w);
        bp2[1] = make_float2(zb.z*w, zb.w*w);
      }
    }
    __syncthreads();

    for (unsigned k = 0; k < cd; ++k) {
      const float2* bp2 = reinterpret_cast<const float2*>(buf + (size_t)(myoff + k) * ST2);
      float2 m0 = bp2[0], m1 = bp2[1];
      a.x += m0.x; a.y += m0.y; a.z += m1.x; a.w += m1.y;
    }
    __syncthreads();
  }

  size_t n = (size_t)bk * RB + tid;
  const float4 rr = *reinterpret_cast<const float4*>(r2 + n * 4);
  float4 o;
  o.x = fmaxf(a.x + rr.x, 0.f);
  o.y = fmaxf(a.y + rr.y, 0.f);
  o.z = fmaxf(a.z + rr.z, 0.f);
  o.w = fmaxf(a.w + rr.w, 0.f);
  *reinterpret_cast<float4*>(embeds + n * 4) = o;
}

// ---------------------------------------------------------------------------
// Final MLP (round-15 version; launched as 2 half-grids for profiling)
// ---------------------------------------------------------------------------
__global__ __launch_bounds__(256, 2) void k_final(
    const float* __restrict__ embeds, const float* __restrict__ gfeat,
    const float* __restrict__ Wg1, const float* __restrict__ bg1,
    const float* __restrict__ Wg2, const float* __restrict__ bg2,
    const float* __restrict__ Wg3, const float* __restrict__ bg3,
    const float* __restrict__ Wo1, const float* __restrict__ bo1,
    const float* __restrict__ Wo2, const float* __restrict__ bo2,
    const float* __restrict__ Wo3, const float* __restrict__ bo3,
    float* __restrict__ out, unsigned bloff) {
  __shared__ float svec[TBF * 232];
  __shared__ float sbuf1[TBF * 128];
  float* sbuf2 = svec;

  const int tid = threadIdx.x;
  const int b0  = (blockIdx.x + bloff) * TBF;

  {
    const float4* src = reinterpret_cast<const float4*>(embeds + (size_t)b0 * 216);
    for (int f4i = tid; f4i < TBF * 54; f4i += 256) {
      int b = f4i / 54;
      int k4 = f4i - b * 54;
      *reinterpret_cast<float4*>(svec + b * 232 + k4 * 4) = src[f4i];
    }
  }
  if (tid < TBF) {
    const float* gf = gfeat + (size_t)(b0 + tid) * GLOBF;
    float gin[16];
#pragma unroll
    for (int i = 0; i < 16; ++i) gin[i] = gf[i];
    float g1[8];
#pragma unroll
    for (int j = 0; j < 8; ++j) {
      float acc = bg1[j];
#pragma unroll
      for (int i = 0; i < 16; ++i) acc = fmaf(gin[i], Wg1[i * 8 + j], acc);
      g1[j] = fmaxf(acc, 0.f);
    }
    float g2[8];
#pragma unroll
    for (int j = 0; j < 8; ++j) {
      float acc = bg2[j];
#pragma unroll
      for (int i = 0; i < 8; ++i) acc = fmaf(g1[i], Wg2[i * 8 + j], acc);
      g2[j] = fmaxf(acc, 0.f);
    }
#pragma unroll
    for (int j = 0; j < 16; ++j) {
      float acc = bg3[j];
#pragma unroll
      for (int i = 0; i < 8; ++i) acc = fmaf(g2[i], Wg3[i * 16 + j], acc);
      svec[tid * 232 + 216 + j] = fmaxf(acc, 0.f);
    }
  }
  __syncthreads();

  const int c0 = (tid & 31) * 4;
  const int rb = (tid >> 5) * 4;

  {
    const float* Wp = Wo1 + c0;
    float4 w0 = *reinterpret_cast<const float4*>(Wp + 0 * 128);
    float4 w1 = *reinterpret_cast<const float4*>(Wp + 1 * 128);
    float4 w2 = *reinterpret_cast<const float4*>(Wp + 2 * 128);
    float4 w3 = *reinterpret_cast<const float4*>(Wp + 3 * 128);
    float acc[4][4];
#pragma unroll
    for (int r = 0; r < 4; ++r)
#pragma unroll
      for (int c = 0; c < 4; ++c) acc[r][c] = 0.f;
    for (int i4 = 0; i4 < 58; ++i4) {
      float4 n0, n1, n2, n3;
      if (i4 < 57) {
        const float* Np = Wp + (size_t)(i4 * 4 + 4) * 128;
        n0 = *reinterpret_cast<const float4*>(Np + 0 * 128);
        n1 = *reinterpret_cast<const float4*>(Np + 1 * 128);
        n2 = *reinterpret_cast<const float4*>(Np + 2 * 128);
        n3 = *reinterpret_cast<const float4*>(Np + 3 * 128);
      }
#pragma unroll
      for (int r = 0; r < 4; ++r) {
        const float4 s = *reinterpret_cast<const float4*>(svec + (rb+r)*232 + i4*4);
        acc[r][0] = fmaf(s.x, w0.x, fmaf(s.y, w1.x, fmaf(s.z, w2.x, fmaf(s.w, w3.x, acc[r][0]))));
        acc[r][1] = fmaf(s.x, w0.y, fmaf(s.y, w1.y, fmaf(s.z, w2.y, fmaf(s.w, w3.y, acc[r][1]))));
        acc[r][2] = fmaf(s.x, w0.z, fmaf(s.y, w1.z, fmaf(s.z, w2.z, fmaf(s.w, w3.z, acc[r][2]))));
        acc[r][3] = fmaf(s.x, w0.w, fmaf(s.y, w1.w, fmaf(s.z, w2.w, fmaf(s.w, w3.w, acc[r][3]))));
      }
      w0 = n0; w1 = n1; w2 = n2; w3 = n3;
    }
    const float4 bv = *reinterpret_cast<const float4*>(bo1 + c0);
#pragma unroll
    for (int r = 0; r < 4; ++r) {
      float4 o;
      o.x = fmaxf(acc[r][0] + bv.x, 0.f);
      o.y = fmaxf(acc[r][1] + bv.y, 0.f);
      o.z = fmaxf(acc[r][2] + bv.z, 0.f);
      o.w = fmaxf(acc[r][3] + bv.w, 0.f);
      *reinterpret_cast<float4*>(sbuf1 + (rb + r) * 128 + c0) = o;
    }
  }
  __syncthreads();

  {
    const float* Wp = Wo2 + c0;
    float4 w0 = *reinterpret_cast<const float4*>(Wp + 0 * 128);
    float4 w1 = *reinterpret_cast<const float4*>(Wp + 1 * 128);
    float4 w2 = *reinterpret_cast<const float4*>(Wp + 2 * 128);
    float4 w3 = *reinterpret_cast<const float4*>(Wp + 3 * 128);
    float acc[4][4];
#pragma unroll
    for (int r = 0; r < 4; ++r)
#pragma unroll
      for (int c = 0; c < 4; ++c) acc[r][c] = 0.f;
    for (int i4 = 0; i4 < 32; ++i4) {
      float4 n0, n1, n2, n3;
      if (i4 < 31) {
        const float* Np = Wp + (size_t)(i4 * 4 + 4) * 128;
        n0 = *reinterpret_cast<const float4*>(Np + 0 * 128);
        n1 = *reinterpret_cast<const float4*>(Np + 1 * 128);
        n2 = *reinterpret_cast<const float4*>(Np + 2 * 128);
        n3 = *reinterpret_cast<const float4*>(Np + 3 * 128);
      }
#pragma unroll
      for (int r = 0; r < 4; ++r) {
        const float4 s = *reinterpret_cast<const float4*>(sbuf1 + (rb+r)*128 + i4*4);
        acc[r][0] = fmaf(s.x, w0.x, fmaf(s.y, w1.x, fmaf(s.z, w2.x, fmaf(s.w, w3.x, acc[r][0]))));
        acc[r][1] = fmaf(s.x, w0.y, fmaf(s.y, w1.y, fmaf(s.z, w2.y, fmaf(s.w, w3.y, acc[r][1]))));
        acc[r][2] = fmaf(s.x, w0.z, fmaf(s.y, w1.z, fmaf(s.z, w2.z, fmaf(s.w, w3.z, acc[r][2]))));
        acc[r][3] = fmaf(s.x, w0.w, fmaf(s.y, w1.w, fmaf(s.z, w2.w, fmaf(s.w, w3.w, acc[r][3]))));
      }
      w0 = n0; w1 = n1; w2 = n2; w3 = n3;
    }
    const float4 bv = *reinterpret_cast<const float4*>(bo2 + c0);
#pragma unroll
    for (int r = 0; r < 4; ++r) {
      float4 o;
      o.x = fmaxf(acc[r][0] + bv.x, 0.f);
      o.y = fmaxf(acc[r][1] + bv.y, 0.f);
      o.z = fmaxf(acc[r][2] + bv.z, 0.f);
      o.w = fmaxf(acc[r][3] + bv.w, 0.f);
      *reinterpret_cast<float4*>(sbuf2 + (rb + r) * 128 + c0) = o;
    }
  }
  __syncthreads();

  {
    const int c2 = (tid & 31) * 2;
    const float* Wp = Wo3 + c2;
    float2 w0 = *reinterpret_cast<const float2*>(Wp + 0 * 64);
    float2 w1 = *reinterpret_cast<const float2*>(Wp + 1 * 64);
    float2 w2 = *reinterpret_cast<const float2*>(Wp + 2 * 64);
    float2 w3 = *reinterpret_cast<const float2*>(Wp + 3 * 64);
    float acc[4][2];
#pragma unroll
    for (int r = 0; r < 4; ++r) { acc[r][0] = 0.f; acc[r][1] = 0.f; }
    for (int i4 = 0; i4 < 32; ++i4) {
      float2 n0, n1, n2, n3;
      if (i4 < 31) {
        const float* Np = Wp + (size_t)(i4 * 4 + 4) * 64;
        n0 = *reinterpret_cast<const float2*>(Np + 0 * 64);
        n1 = *reinterpret_cast<const float2*>(Np + 1 * 64);
        n2 = *reinterpret_cast<const float2*>(Np + 2 * 64);
        n3 = *reinterpret_cast<const float2*>(Np + 3 * 64);
      }
#pragma unroll
      for (int r = 0; r < 4; ++r) {
        const float4 s = *reinterpret_cast<const float4*>(sbuf2 + (rb+r)*128 + i4*4);
        acc[r][0] = fmaf(s.x, w0.x, fmaf(s.y, w1.x, fmaf(s.z, w2.x, fmaf(s.w, w3.x, acc[r][0]))));
        acc[r][1] = fmaf(s.x, w0.y, fmaf(s.y, w1.y, fmaf(s.z, w2.y, fmaf(s.w, w3.y, acc[r][1]))));
      }
      w0 = n0; w1 = n1; w2 = n2; w3 = n3;
    }
    const float2 bv = *reinterpret_cast<const float2*>(bo3 + c2);
#pragma unroll
    for (int r = 0; r < 4; ++r) {
      float2 o;
      o.x = acc[r][0] + bv.x;
      o.y = acc[r][1] + bv.y;
      *reinterpret_cast<float2*>(out + (size_t)(b0 + rb + r) * 64 + c2) = o;
    }
  }
}

// ---------------------------------------------------------------------------
extern "C" void kernel_launch(void* const* d_in, const int* in_sizes, int n_in,
                              void* d_out, int out_size, void* d_ws, size_t ws_size,
                              hipStream_t stream) {
  const float* x      = (const float*)d_in[0];
  const int*   ei     = (const int*)d_in[1];
  const float* ea     = (const float*)d_in[2];
  const float* gfeat  = (const float*)d_in[3];
  const float* W1_rel = (const float*)d_in[5];
  const float* b1     = (const float*)d_in[6];
  const float* W1_root= (const float*)d_in[7];
  const float* W2_rel = (const float*)d_in[8];
  const float* b2     = (const float*)d_in[9];
  const float* W2_root= (const float*)d_in[10];
  const float* Wg1 = (const float*)d_in[11];
  const float* bg1 = (const float*)d_in[12];
  const float* Wg2 = (const float*)d_in[13];
  const float* bg2 = (const float*)d_in[14];
  const float* Wg3 = (const float*)d_in[15];
  const float* bg3 = (const float*)d_in[16];
  const float* Wo1 = (const float*)d_in[17];
  const float* bo1 = (const float*)d_in[18];
  const float* Wo2 = (const float*)d_in[19];
  const float* bo2 = (const float*)d_in[20];
  const float* Wo3 = (const float*)d_in[21];
  const float* bo3 = (const float*)d_in[22];
  float* outp = (float*)d_out;

  // workspace (~166 MB)
  uint2*    rec    = (uint2*)d_ws;                         // NE*8B
  uint2*    recA   = rec + NE;                             // NE*8B
  unsigned char* dhiA = (unsigned char*)(recA + NE);       // NE*1B
  float*    z2     = (float*)(dhiA + NE);                  // NN*4 f
  float*    r2     = z2 + (size_t)NN * 4;                  // NN*4 f
  float*    embeds = r2 + (size_t)NN * 4;                  // NN*4 f
  unsigned* hist   = (unsigned*)(embeds + (size_t)NN * 4); // NBK
  unsigned* base   = hist + NBK;                           // NBK+1
  unsigned* cursorB= base + NBK + 1;                       // NBK
  unsigned* curA   = cursorB + NBK;                        // NCL

  hipMemsetAsync(hist, 0, NBK * sizeof(unsigned), stream);
  k_histl <<<HB, 256, 0, stream>>>(ei, hist);
  k_scan2 <<<1, 1024, 0, stream>>>(hist, base, cursorB, curA);
  k_placeA<<<NBA, 256, 0, stream>>>(ei, ea, curA, recA, dhiA);
  k_placeB<<<NCL * CPB, 256, 0, stream>>>(recA, dhiA, base, cursorB, rec);
  for (unsigned q = 0; q < 4; ++q)
    k_conv1s<<<QBK, 256, 0, stream>>>(rec, base, x, W1_rel, b1, W1_root,
                                      W2_rel, b2, W2_root, z2, r2, q * QBK);
  for (unsigned q = 0; q < 4; ++q)
    k_conv2s<<<QBK, 256, 0, stream>>>(rec, base, z2, r2, embeds, q * QBK);
  for (unsigned hhalf = 0; hhalf < 2; ++hhalf)
    k_final<<<BD / TBF / 2, 256, 0, stream>>>(embeds, gfeat,
                                              Wg1, bg1, Wg2, bg2, Wg3, bg3,
                                              Wo1, bo1, Wo2, bo2, Wo3, bo3,
                                              outp, hhalf * (BD / TBF / 2));
}

// Round 19
// 479.923 us; speedup vs baseline: 1.7148x; 1.0300x over previous
//
#include <hip/hip_runtime.h>

// Problem constants
#define BD   32768
#define NPG  54
#define NN   (BD * NPG)          // 1,769,472 nodes
#define NE   (BD * 144)          // 4,718,592 edges
#define DIN  16
#define DH   32
#define GLOBF 16
#define TBF  32                  // boards per final block
#define RB   256                 // nodes per dst bucket
#define NBK  (NN / RB)           // 6912 buckets
#define QBK  (NBK / 4)
#define SRCM 0x1FFFFFu           // 21-bit src mask
#define CH1  256                 // conv1 sort-chunk (1 rec/thread; LDS 23.6KB -> 6 blocks/CU)
#define CH2  512                 // conv2 sort-chunk
#define STW  18                  // conv1 sort-row stride (floats): 72B, b64-aligned
#define ST2  6                   // conv2 sort-row stride (floats): 24B, b64-aligned
#define HB   256                 // hist blocks
#define EB   4096                // edges per place block
#define NBA  (NE / EB)           // 1152
#define NCL  108                 // classes = d>>14 (64 buckets each)
#define CPB  12                  // placeB chunks per class

// ---------------------------------------------------------------------------
// Pass 1: dst-bucket histogram (LDS-staged)
// ---------------------------------------------------------------------------
__global__ __launch_bounds__(256) void k_histl(const int* __restrict__ ei,
                                               unsigned* __restrict__ hist) {
  __shared__ unsigned h[NBK];                            // 27648 B
  const int tid = threadIdx.x;
  for (int i = tid; i < NBK; i += 256) h[i] = 0u;
  __syncthreads();
  const unsigned base = blockIdx.x * (NE / HB);
  for (unsigned i = tid; i < NE / HB; i += 256u) {
    unsigned d = (unsigned)ei[NE + base + i];
    atomicAdd(&h[d >> 8], 1u);
  }
  __syncthreads();
  for (int i = tid; i < NBK; i += 256)
    if (h[i]) atomicAdd(&hist[i], h[i]);
}

// ---------------------------------------------------------------------------
// Pass 2: exclusive scan; also inits class cursors for placeA
// ---------------------------------------------------------------------------
__global__ __launch_bounds__(1024) void k_scan2(const unsigned* __restrict__ hist,
                                                unsigned* __restrict__ base,
                                                unsigned* __restrict__ cursorB,
                                                unsigned* __restrict__ curA) {
  __shared__ unsigned s[1024];
  const int tid = threadIdx.x;
  unsigned loc[7]; unsigned run = 0;
#pragma unroll
  for (int j = 0; j < 7; ++j) {
    int idx = tid * 7 + j;
    unsigned v = (idx < NBK) ? hist[idx] : 0u;
    loc[j] = run; run += v;
  }
  s[tid] = run; __syncthreads();
  for (int off = 1; off < 1024; off <<= 1) {
    unsigned t = (tid >= off) ? s[tid - off] : 0u;
    __syncthreads(); s[tid] += t; __syncthreads();
  }
  unsigned cb = tid ? s[tid - 1] : 0u;
#pragma unroll
  for (int j = 0; j < 7; ++j) {
    int idx = tid * 7 + j;
    if (idx < NBK) {
      unsigned b = cb + loc[j];
      base[idx] = b; cursorB[idx] = b;
      if ((idx & 63) == 0) curA[idx >> 6] = b;
    }
  }
  if (tid == 1023) base[NBK] = s[1023];                  // = NE
}

// ---------------------------------------------------------------------------
// placeA: LDS counting sort of 4096 edges by class (d>>14), run-claim flush
// ---------------------------------------------------------------------------
__global__ __launch_bounds__(256) void k_placeA(
    const int* __restrict__ ei, const float* __restrict__ ea,
    unsigned* __restrict__ curA, uint2* __restrict__ recA,
    unsigned char* __restrict__ dhiA) {
  __shared__ uint2 buf[EB];                              // 32768 B
  __shared__ unsigned char cls8[EB];                     // 4096 B
  __shared__ unsigned char dh6[EB];                      // 4096 B
  __shared__ unsigned h[NCL];
  __shared__ unsigned sb[NCL];
  __shared__ unsigned posL[NCL];
  const int tid = threadIdx.x;
  const unsigned eb = blockIdx.x * (unsigned)EB;

  for (int k = tid; k < NCL; k += 256) h[k] = 0u;
  __syncthreads();

  unsigned rkcls[16];                                    // rank(12b) | class<<12
#pragma unroll
  for (int i = 0; i < 16; ++i) {
    unsigned e = eb + i * 256u + tid;
    unsigned d = (unsigned)ei[NE + e];
    unsigned c = d >> 14;
    unsigned rk = atomicAdd(&h[c], 1u);
    rkcls[i] = rk | (c << 12);
  }
  __syncthreads();
  if (tid == 0) {
    unsigned runl = 0;
    for (int k = 0; k < NCL; ++k) { sb[k] = runl; runl += h[k]; }
  }
  __syncthreads();
  if (tid < NCL) posL[tid] = atomicAdd(&curA[tid], h[tid]);
  __syncthreads();

#pragma unroll
  for (int i = 0; i < 16; ++i) {
    unsigned e = eb + i * 256u + tid;
    unsigned sv = (unsigned)ei[e];
    unsigned d  = (unsigned)ei[NE + e];
    float    w  = ea[e];
    unsigned c  = rkcls[i] >> 12;
    unsigned slot = sb[c] + (rkcls[i] & 0xFFFu);
    buf[slot]  = make_uint2(sv | ((d & 255u) << 21), __float_as_uint(w));
    cls8[slot] = (unsigned char)c;
    dh6[slot]  = (unsigned char)((d >> 8) & 63u);
  }
  __syncthreads();

  for (int i = tid; i < EB; i += 256) {
    unsigned c = cls8[i];
    unsigned pos = posL[c] + (unsigned)i - sb[c];
    recA[pos] = buf[i];
    dhiA[pos] = dh6[i];
  }
}

// ---------------------------------------------------------------------------
// placeB: within class, sort 4096-record chunk by bucket-in-class, run-claims
// ---------------------------------------------------------------------------
__global__ __launch_bounds__(256) void k_placeB(
    const uint2* __restrict__ recA, const unsigned char* __restrict__ dhiA,
    const unsigned* __restrict__ base, unsigned* __restrict__ curB,
    uint2* __restrict__ rec) {
  __shared__ uint2 buf[EB];                              // 32768 B
  __shared__ unsigned char dh6[EB];                      // 4096 B
  __shared__ unsigned h[64];
  __shared__ unsigned sb[64];
  __shared__ unsigned posL[64];
  const int tid = threadIdx.x;
  const unsigned c = blockIdx.x / CPB;
  const unsigned j = blockIdx.x % CPB;
  const unsigned clsLo = base[c * 64];
  const unsigned clsHi = base[c * 64 + 64];
  const unsigned lo = clsLo + j * (unsigned)EB;
  if (lo >= clsHi) return;
  const unsigned hi = min(lo + (unsigned)EB, clsHi);
  const unsigned cnt = hi - lo;

  if (tid < 64) h[tid] = 0u;
  __syncthreads();

  unsigned rkd[16];
#pragma unroll
  for (int i = 0; i < 16; ++i) {
    unsigned idx = lo + i * 256u + tid;
    rkd[i] = 0xFFFFFFFFu;
    if (idx < hi) {
      unsigned dh = dhiA[idx];
      unsigned rk = atomicAdd(&h[dh], 1u);
      rkd[i] = rk | (dh << 12);
    }
  }
  __syncthreads();
  if (tid == 0) {
    unsigned runl = 0;
    for (int k = 0; k < 64; ++k) { sb[k] = runl; runl += h[k]; }
  }
  __syncthreads();
  if (tid < 64) posL[tid] = atomicAdd(&curB[c * 64u + tid], h[tid]);
  __syncthreads();

#pragma unroll
  for (int i = 0; i < 16; ++i) {
    if (rkd[i] != 0xFFFFFFFFu) {
      unsigned idx = lo + i * 256u + tid;
      unsigned dh = rkd[i] >> 12;
      unsigned slot = sb[dh] + (rkd[i] & 0xFFFu);
      buf[slot] = recA[idx];
      dh6[slot] = (unsigned char)dh;
    }
  }
  __syncthreads();

  for (unsigned i = tid; i < cnt; i += 256) {
    unsigned k = dh6[i];
    unsigned pos = posL[k] + i - sb[k];
    rec[pos] = buf[i];
  }
}

// shfl-based exclusive scan helper (256 threads, packed 16+16 fields)
__device__ __forceinline__ unsigned block_excl_scan_packed(
    unsigned packed, unsigned* wsum, int tid) {
  unsigned v = packed;
#pragma unroll
  for (int off = 1; off < 64; off <<= 1) {
    unsigned t = __shfl_up(v, off, 64);
    if ((tid & 63) >= off) v += t;
  }
  if ((tid & 63) == 63) wsum[tid >> 6] = v;
  __syncthreads();
  const int wid = tid >> 6;
  unsigned wpre = 0;
#pragma unroll
  for (int wmid = 0; wmid < 4; ++wmid)
    if (wmid < wid) wpre += wsum[wmid];
  return v + wpre - packed;            // exclusive
}

// ---------------------------------------------------------------------------
// Conv1 (dual counting sort; CH1=256, 1 record/thread, ~23.6KB LDS ->
// 6 blocks/CU) -> z2, r2
// ---------------------------------------------------------------------------
__global__ __launch_bounds__(256) void k_conv1s(
    const uint2* __restrict__ rec, const unsigned* __restrict__ base,
    const float* __restrict__ x,
    const float* __restrict__ W1_rel, const float* __restrict__ b1,
    const float* __restrict__ W1_root,
    const float* __restrict__ W2_rel, const float* __restrict__ b2,
    const float* __restrict__ W2_root,
    float* __restrict__ z2, float* __restrict__ r2, unsigned bkoff) {
  __shared__ float buf[CH1 * STW];       // 18432 B
  __shared__ uint2 prm[CH1];             // 2048 B
  __shared__ unsigned hd[256];
  __shared__ unsigned hs[256];
  __shared__ unsigned sc[256];
  __shared__ unsigned wsum[4];
  const int tid = threadIdx.x;
  const unsigned bk = blockIdx.x + bkoff;
  const unsigned r0 = base[bk], r1 = base[bk + 1];

  float a[16];
#pragma unroll
  for (int i = 0; i < 16; ++i) a[i] = 0.f;

  for (unsigned c0 = r0; c0 < r1; c0 += CH1) {
    const unsigned validCnt = min((unsigned)CH1, r1 - c0);
    hd[tid] = 0u; hs[tid] = 0u;
    __syncthreads();

    const unsigned i0 = c0 + tid;
    const bool qa = i0 < r1;
    unsigned srcA = 0, la = 0, sa = 0, wa = 0, rkda = 0, rksa = 0;
    if (qa) {
      uint2 ra = rec[i0];
      srcA = ra.x & SRCM; la = ra.x >> 21; sa = srcA >> 13; wa = ra.y;
      rkda = atomicAdd(&hd[la], 1u); rksa = atomicAdd(&hs[sa], 1u);
    }
    __syncthreads();

    const unsigned cd = hd[tid];
    const unsigned packed = cd | (hs[tid] << 16);
    const unsigned exclP = block_excl_scan_packed(packed, wsum, tid);
    const unsigned myoff = exclP & 0xffffu;
    sc[tid] = exclP;
    __syncthreads();

    if (qa) {
      unsigned dslot = (sc[la] & 0xffffu) + rkda;
      unsigned spos  = (sc[sa] >> 16) + rksa;
      prm[spos] = make_uint2(srcA | (dslot << 21), wa);
    }
    __syncthreads();

    // gather phase in ascending-src order; scatter as 8x float2 (b64)
    if (tid < (int)validCnt) {
      uint2 pa = prm[tid];
      const float4* xp = reinterpret_cast<const float4*>(x + (size_t)(pa.x & SRCM) * 16);
      float4 xa0 = xp[0], xa1 = xp[1], xa2 = xp[2], xa3 = xp[3];
      float w = __uint_as_float(pa.y);
      float2* bp2 = reinterpret_cast<float2*>(buf + (size_t)(pa.x >> 21) * STW);
      bp2[0] = make_float2(xa0.x*w, xa0.y*w);
      bp2[1] = make_float2(xa0.z*w, xa0.w*w);
      bp2[2] = make_float2(xa1.x*w, xa1.y*w);
      bp2[3] = make_float2(xa1.z*w, xa1.w*w);
      bp2[4] = make_float2(xa2.x*w, xa2.y*w);
      bp2[5] = make_float2(xa2.z*w, xa2.w*w);
      bp2[6] = make_float2(xa3.x*w, xa3.y*w);
      bp2[7] = make_float2(xa3.z*w, xa3.w*w);
    }
    __syncthreads();

    for (unsigned k = 0; k < cd; ++k) {
      const float2* bp2 = reinterpret_cast<const float2*>(buf + (size_t)(myoff + k) * STW);
      float2 m0 = bp2[0], m1 = bp2[1], m2 = bp2[2], m3 = bp2[3];
      float2 m4 = bp2[4], m5 = bp2[5], m6 = bp2[6], m7 = bp2[7];
      a[0]  += m0.x; a[1]  += m0.y; a[2]  += m1.x; a[3]  += m1.y;
      a[4]  += m2.x; a[5]  += m2.y; a[6]  += m3.x; a[7]  += m3.y;
      a[8]  += m4.x; a[9]  += m4.y; a[10] += m5.x; a[11] += m5.y;
      a[12] += m6.x; a[13] += m6.y; a[14] += m7.x; a[15] += m7.y;
    }
    __syncthreads();
  }

  size_t n = (size_t)bk * RB + tid;
  float xv[16];
  {
    const float4* xp = reinterpret_cast<const float4*>(x + n * 16);
#pragma unroll
    for (int q = 0; q < 4; ++q) {
      float4 t2 = xp[q];
      xv[4*q+0] = t2.x; xv[4*q+1] = t2.y; xv[4*q+2] = t2.z; xv[4*q+3] = t2.w;
    }
  }
  float h[DH];
#pragma unroll
  for (int j = 0; j < DH; ++j) h[j] = b1[j];
#pragma unroll
  for (int i = 0; i < DIN; ++i) {
    float ai = a[i], xi = xv[i];
#pragma unroll
    for (int j = 0; j < DH; ++j)
      h[j] = fmaf(ai, W1_rel[i * DH + j], fmaf(xi, W1_root[i * DH + j], h[j]));
  }
#pragma unroll
  for (int j = 0; j < DH; ++j) h[j] = fmaxf(h[j], 0.f);
  float z[4] = {0.f, 0.f, 0.f, 0.f};
  float r[4] = {b2[0], b2[1], b2[2], b2[3]};
#pragma unroll
  for (int j = 0; j < DH; ++j) {
    float hj = h[j];
#pragma unroll
    for (int k = 0; k < 4; ++k) {
      z[k] = fmaf(hj, W2_rel[j * 4 + k], z[k]);
      r[k] = fmaf(hj, W2_root[j * 4 + k], r[k]);
    }
  }
  *reinterpret_cast<float4*>(z2 + n * 4) = make_float4(z[0], z[1], z[2], z[3]);
  *reinterpret_cast<float4*>(r2 + n * 4) = make_float4(r[0], r[1], r[2], r[3]);
}

// ---------------------------------------------------------------------------
// Conv2 (dual counting sort; CH2=512, ST2=6 float2 rows)
// ---------------------------------------------------------------------------
__global__ __launch_bounds__(256) void k_conv2s(
    const uint2* __restrict__ rec, const unsigned* __restrict__ base,
    const float* __restrict__ z2, const float* __restrict__ r2,
    float* __restrict__ embeds, unsigned bkoff) {
  __shared__ float buf[CH2 * ST2];       // 12288 B
  __shared__ uint2 prm[CH2];
  __shared__ unsigned hd[256];
  __shared__ unsigned hs[256];
  __shared__ unsigned sc[256];
  __shared__ unsigned wsum[4];
  const int tid = threadIdx.x;
  const unsigned bk = blockIdx.x + bkoff;
  const unsigned r0 = base[bk], r1 = base[bk + 1];

  float4 a = make_float4(0.f, 0.f, 0.f, 0.f);

  for (unsigned c0 = r0; c0 < r1; c0 += CH2) {
    const unsigned validCnt = min((unsigned)CH2, r1 - c0);
    hd[tid] = 0u; hs[tid] = 0u;
    __syncthreads();

    const unsigned i0 = c0 + tid;
    const unsigned i1 = c0 + 256u + tid;
    const bool qa = i0 < r1;
    const bool qb = i1 < r1;
    unsigned srcA = 0, srcB = 0, la = 0, lb = 0, sa = 0, sb2 = 0;
    unsigned wa = 0, wb = 0, rkda = 0, rkdb = 0, rksa = 0, rksb = 0;
    if (qa) {
      uint2 ra = rec[i0];
      srcA = ra.x & SRCM; la = ra.x >> 21; sa = srcA >> 13; wa = ra.y;
    }
    if (qb) {
      uint2 rb = rec[i1];
      srcB = rb.x & SRCM; lb = rb.x >> 21; sb2 = srcB >> 13; wb = rb.y;
    }
    if (qa) { rkda = atomicAdd(&hd[la], 1u); rksa = atomicAdd(&hs[sa], 1u); }
    if (qb) { rkdb = atomicAdd(&hd[lb], 1u); rksb = atomicAdd(&hs[sb2], 1u); }
    __syncthreads();

    const unsigned cd = hd[tid];
    const unsigned packed = cd | (hs[tid] << 16);
    const unsigned exclP = block_excl_scan_packed(packed, wsum, tid);
    const unsigned myoff = exclP & 0xffffu;
    sc[tid] = exclP;
    __syncthreads();

    if (qa) {
      unsigned dslot = (sc[la] & 0xffffu) + rkda;
      unsigned spos  = (sc[sa] >> 16) + rksa;
      prm[spos] = make_uint2(srcA | (dslot << 21), wa);
    }
    if (qb) {
      unsigned dslot = (sc[lb] & 0xffffu) + rkdb;
      unsigned spos  = (sc[sb2] >> 16) + rksb;
      prm[spos] = make_uint2(srcB | (dslot << 21), wb);
    }
    __syncthreads();

    {
      const bool ga = tid < validCnt;
      const bool gb = tid + 256u < validCnt;
      uint2 pa, pb;
      float4 za, zb;
      if (ga) {
        pa = prm[tid];
        za = *reinterpret_cast<const float4*>(z2 + (size_t)(pa.x & SRCM) * 4);
      }
      if (gb) {
        pb = prm[tid + 256];
        zb = *reinterpret_cast<const float4*>(z2 + (size_t)(pb.x & SRCM) * 4);
      }
      if (ga) {
        float w = __uint_as_float(pa.y);
        float2* bp2 = reinterpret_cast<float2*>(buf + (size_t)(pa.x >> 21) * ST2);
        bp2[0] = make_float2(za.x*w, za.y*w);
        bp2[1] = make_float2(za.z*w, za.w*w);
      }
      if (gb) {
        float w = __uint_as_float(pb.y);
        float2* bp2 = reinterpret_cast<float2*>(buf + (size_t)(pb.x >> 21) * ST2);
        bp2[0] = make_float2(zb.x*w, zb.y*w);
        bp2[1] = make_float2(zb.z*w, zb.w*w);
      }
    }
    __syncthreads();

    for (unsigned k = 0; k < cd; ++k) {
      const float2* bp2 = reinterpret_cast<const float2*>(buf + (size_t)(myoff + k) * ST2);
      float2 m0 = bp2[0], m1 = bp2[1];
      a.x += m0.x; a.y += m0.y; a.z += m1.x; a.w += m1.y;
    }
    __syncthreads();
  }

  size_t n = (size_t)bk * RB + tid;
  const float4 rr = *reinterpret_cast<const float4*>(r2 + n * 4);
  float4 o;
  o.x = fmaxf(a.x + rr.x, 0.f);
  o.y = fmaxf(a.y + rr.y, 0.f);
  o.z = fmaxf(a.z + rr.z, 0.f);
  o.w = fmaxf(a.w + rr.w, 0.f);
  *reinterpret_cast<float4*>(embeds + n * 4) = o;
}

// ---------------------------------------------------------------------------
// Final MLP (round-15 version; 2 half-grids)
// ---------------------------------------------------------------------------
__global__ __launch_bounds__(256, 2) void k_final(
    const float* __restrict__ embeds, const float* __restrict__ gfeat,
    const float* __restrict__ Wg1, const float* __restrict__ bg1,
    const float* __restrict__ Wg2, const float* __restrict__ bg2,
    const float* __restrict__ Wg3, const float* __restrict__ bg3,
    const float* __restrict__ Wo1, const float* __restrict__ bo1,
    const float* __restrict__ Wo2, const float* __restrict__ bo2,
    const float* __restrict__ Wo3, const float* __restrict__ bo3,
    float* __restrict__ out, unsigned bloff) {
  __shared__ float svec[TBF * 232];
  __shared__ float sbuf1[TBF * 128];
  float* sbuf2 = svec;

  const int tid = threadIdx.x;
  const int b0  = (blockIdx.x + bloff) * TBF;

  {
    const float4* src = reinterpret_cast<const float4*>(embeds + (size_t)b0 * 216);
    for (int f4i = tid; f4i < TBF * 54; f4i += 256) {
      int b = f4i / 54;
      int k4 = f4i - b * 54;
      *reinterpret_cast<float4*>(svec + b * 232 + k4 * 4) = src[f4i];
    }
  }
  if (tid < TBF) {
    const float* gf = gfeat + (size_t)(b0 + tid) * GLOBF;
    float gin[16];
#pragma unroll
    for (int i = 0; i < 16; ++i) gin[i] = gf[i];
    float g1[8];
#pragma unroll
    for (int j = 0; j < 8; ++j) {
      float acc = bg1[j];
#pragma unroll
      for (int i = 0; i < 16; ++i) acc = fmaf(gin[i], Wg1[i * 8 + j], acc);
      g1[j] = fmaxf(acc, 0.f);
    }
    float g2[8];
#pragma unroll
    for (int j = 0; j < 8; ++j) {
      float acc = bg2[j];
#pragma unroll
      for (int i = 0; i < 8; ++i) acc = fmaf(g1[i], Wg2[i * 8 + j], acc);
      g2[j] = fmaxf(acc, 0.f);
    }
#pragma unroll
    for (int j = 0; j < 16; ++j) {
      float acc = bg3[j];
#pragma unroll
      for (int i = 0; i < 8; ++i) acc = fmaf(g2[i], Wg3[i * 16 + j], acc);
      svec[tid * 232 + 216 + j] = fmaxf(acc, 0.f);
    }
  }
  __syncthreads();

  const int c0 = (tid & 31) * 4;
  const int rb = (tid >> 5) * 4;

  {
    const float* Wp = Wo1 + c0;
    float4 w0 = *reinterpret_cast<const float4*>(Wp + 0 * 128);
    float4 w1 = *reinterpret_cast<const float4*>(Wp + 1 * 128);
    float4 w2 = *reinterpret_cast<const float4*>(Wp + 2 * 128);
    float4 w3 = *reinterpret_cast<const float4*>(Wp + 3 * 128);
    float acc[4][4];
#pragma unroll
    for (int r = 0; r < 4; ++r)
#pragma unroll
      for (int c = 0; c < 4; ++c) acc[r][c] = 0.f;
    for (int i4 = 0; i4 < 58; ++i4) {
      float4 n0, n1, n2, n3;
      if (i4 < 57) {
        const float* Np = Wp + (size_t)(i4 * 4 + 4) * 128;
        n0 = *reinterpret_cast<const float4*>(Np + 0 * 128);
        n1 = *reinterpret_cast<const float4*>(Np + 1 * 128);
        n2 = *reinterpret_cast<const float4*>(Np + 2 * 128);
        n3 = *reinterpret_cast<const float4*>(Np + 3 * 128);
      }
#pragma unroll
      for (int r = 0; r < 4; ++r) {
        const float4 s = *reinterpret_cast<const float4*>(svec + (rb+r)*232 + i4*4);
        acc[r][0] = fmaf(s.x, w0.x, fmaf(s.y, w1.x, fmaf(s.z, w2.x, fmaf(s.w, w3.x, acc[r][0]))));
        acc[r][1] = fmaf(s.x, w0.y, fmaf(s.y, w1.y, fmaf(s.z, w2.y, fmaf(s.w, w3.y, acc[r][1]))));
        acc[r][2] = fmaf(s.x, w0.z, fmaf(s.y, w1.z, fmaf(s.z, w2.z, fmaf(s.w, w3.z, acc[r][2]))));
        acc[r][3] = fmaf(s.x, w0.w, fmaf(s.y, w1.w, fmaf(s.z, w2.w, fmaf(s.w, w3.w, acc[r][3]))));
      }
      w0 = n0; w1 = n1; w2 = n2; w3 = n3;
    }
    const float4 bv = *reinterpret_cast<const float4*>(bo1 + c0);
#pragma unroll
    for (int r = 0; r < 4; ++r) {
      float4 o;
      o.x = fmaxf(acc[r][0] + bv.x, 0.f);
      o.y = fmaxf(acc[r][1] + bv.y, 0.f);
      o.z = fmaxf(acc[r][2] + bv.z, 0.f);
      o.w = fmaxf(acc[r][3] + bv.w, 0.f);
      *reinterpret_cast<float4*>(sbuf1 + (rb + r) * 128 + c0) = o;
    }
  }
  __syncthreads();

  {
    const float* Wp = Wo2 + c0;
    float4 w0 = *reinterpret_cast<const float4*>(Wp + 0 * 128);
    float4 w1 = *reinterpret_cast<const float4*>(Wp + 1 * 128);
    float4 w2 = *reinterpret_cast<const float4*>(Wp + 2 * 128);
    float4 w3 = *reinterpret_cast<const float4*>(Wp + 3 * 128);
    float acc[4][4];
#pragma unroll
    for (int r = 0; r < 4; ++r)
#pragma unroll
      for (int c = 0; c < 4; ++c) acc[r][c] = 0.f;
    for (int i4 = 0; i4 < 32; ++i4) {
      float4 n0, n1, n2, n3;
      if (i4 < 31) {
        const float* Np = Wp + (size_t)(i4 * 4 + 4) * 128;
        n0 = *reinterpret_cast<const float4*>(Np + 0 * 128);
        n1 = *reinterpret_cast<const float4*>(Np + 1 * 128);
        n2 = *reinterpret_cast<const float4*>(Np + 2 * 128);
        n3 = *reinterpret_cast<const float4*>(Np + 3 * 128);
      }
#pragma unroll
      for (int r = 0; r < 4; ++r) {
        const float4 s = *reinterpret_cast<const float4*>(sbuf1 + (rb+r)*128 + i4*4);
        acc[r][0] = fmaf(s.x, w0.x, fmaf(s.y, w1.x, fmaf(s.z, w2.x, fmaf(s.w, w3.x, acc[r][0]))));
        acc[r][1] = fmaf(s.x, w0.y, fmaf(s.y, w1.y, fmaf(s.z, w2.y, fmaf(s.w, w3.y, acc[r][1]))));
        acc[r][2] = fmaf(s.x, w0.z, fmaf(s.y, w1.z, fmaf(s.z, w2.z, fmaf(s.w, w3.z, acc[r][2]))));
        acc[r][3] = fmaf(s.x, w0.w, fmaf(s.y, w1.w, fmaf(s.z, w2.w, fmaf(s.w, w3.w, acc[r][3]))));
      }
      w0 = n0; w1 = n1; w2 = n2; w3 = n3;
    }
    const float4 bv = *reinterpret_cast<const float4*>(bo2 + c0);
#pragma unroll
    for (int r = 0; r < 4; ++r) {
      float4 o;
      o.x = fmaxf(acc[r][0] + bv.x, 0.f);
      o.y = fmaxf(acc[r][1] + bv.y, 0.f);
      o.z = fmaxf(acc[r][2] + bv.z, 0.f);
      o.w = fmaxf(acc[r][3] + bv.w, 0.f);
      *reinterpret_cast<float4*>(sbuf2 + (rb + r) * 128 + c0) = o;
    }
  }
  __syncthreads();

  {
    const int c2 = (tid & 31) * 2;
    const float* Wp = Wo3 + c2;
    float2 w0 = *reinterpret_cast<const float2*>(Wp + 0 * 64);
    float2 w1 = *reinterpret_cast<const float2*>(Wp + 1 * 64);
    float2 w2 = *reinterpret_cast<const float2*>(Wp + 2 * 64);
    float2 w3 = *reinterpret_cast<const float2*>(Wp + 3 * 64);
    float acc[4][2];
#pragma unroll
    for (int r = 0; r < 4; ++r) { acc[r][0] = 0.f; acc[r][1] = 0.f; }
    for (int i4 = 0; i4 < 32; ++i4) {
      float2 n0, n1, n2, n3;
      if (i4 < 31) {
        const float* Np = Wp + (size_t)(i4 * 4 + 4) * 64;
        n0 = *reinterpret_cast<const float2*>(Np + 0 * 64);
        n1 = *reinterpret_cast<const float2*>(Np + 1 * 64);
        n2 = *reinterpret_cast<const float2*>(Np + 2 * 64);
        n3 = *reinterpret_cast<const float2*>(Np + 3 * 64);
      }
#pragma unroll
      for (int r = 0; r < 4; ++r) {
        const float4 s = *reinterpret_cast<const float4*>(sbuf2 + (rb+r)*128 + i4*4);
        acc[r][0] = fmaf(s.x, w0.x, fmaf(s.y, w1.x, fmaf(s.z, w2.x, fmaf(s.w, w3.x, acc[r][0]))));
        acc[r][1] = fmaf(s.x, w0.y, fmaf(s.y, w1.y, fmaf(s.z, w2.y, fmaf(s.w, w3.y, acc[r][1]))));
      }
      w0 = n0; w1 = n1; w2 = n2; w3 = n3;
    }
    const float2 bv = *reinterpret_cast<const float2*>(bo3 + c2);
#pragma unroll
    for (int r = 0; r < 4; ++r) {
      float2 o;
      o.x = acc[r][0] + bv.x;
      o.y = acc[r][1] + bv.y;
      *reinterpret_cast<float2*>(out + (size_t)(b0 + rb + r) * 64 + c2) = o;
    }
  }
}

// ---------------------------------------------------------------------------
extern "C" void kernel_launch(void* const* d_in, const int* in_sizes, int n_in,
                              void* d_out, int out_size, void* d_ws, size_t ws_size,
                              hipStream_t stream) {
  const float* x      = (const float*)d_in[0];
  const int*   ei     = (const int*)d_in[1];
  const float* ea     = (const float*)d_in[2];
  const float* gfeat  = (const float*)d_in[3];
  const float* W1_rel = (const float*)d_in[5];
  const float* b1     = (const float*)d_in[6];
  const float* W1_root= (const float*)d_in[7];
  const float* W2_rel = (const float*)d_in[8];
  const float* b2     = (const float*)d_in[9];
  const float* W2_root= (const float*)d_in[10];
  const float* Wg1 = (const float*)d_in[11];
  const float* bg1 = (const float*)d_in[12];
  const float* Wg2 = (const float*)d_in[13];
  const float* bg2 = (const float*)d_in[14];
  const float* Wg3 = (const float*)d_in[15];
  const float* bg3 = (const float*)d_in[16];
  const float* Wo1 = (const float*)d_in[17];
  const float* bo1 = (const float*)d_in[18];
  const float* Wo2 = (const float*)d_in[19];
  const float* bo2 = (const float*)d_in[20];
  const float* Wo3 = (const float*)d_in[21];
  const float* bo3 = (const float*)d_in[22];
  float* outp = (float*)d_out;

  // workspace (~166 MB)
  uint2*    rec    = (uint2*)d_ws;                         // NE*8B
  uint2*    recA   = rec + NE;                             // NE*8B
  unsigned char* dhiA = (unsigned char*)(recA + NE);       // NE*1B
  float*    z2     = (float*)(dhiA + NE);                  // NN*4 f
  float*    r2     = z2 + (size_t)NN * 4;                  // NN*4 f
  float*    embeds = r2 + (size_t)NN * 4;                  // NN*4 f
  unsigned* hist   = (unsigned*)(embeds + (size_t)NN * 4); // NBK
  unsigned* base   = hist + NBK;                           // NBK+1
  unsigned* cursorB= base + NBK + 1;                       // NBK
  unsigned* curA   = cursorB + NBK;                        // NCL

  hipMemsetAsync(hist, 0, NBK * sizeof(unsigned), stream);
  k_histl <<<HB, 256, 0, stream>>>(ei, hist);
  k_scan2 <<<1, 1024, 0, stream>>>(hist, base, cursorB, curA);
  k_placeA<<<NBA, 256, 0, stream>>>(ei, ea, curA, recA, dhiA);
  k_placeB<<<NCL * CPB, 256, 0, stream>>>(recA, dhiA, base, cursorB, rec);
  for (unsigned q = 0; q < 4; ++q)
    k_conv1s<<<QBK, 256, 0, stream>>>(rec, base, x, W1_rel, b1, W1_root,
                                      W2_rel, b2, W2_root, z2, r2, q * QBK);
  for (unsigned q = 0; q < 4; ++q)
    k_conv2s<<<QBK, 256, 0, stream>>>(rec, base, z2, r2, embeds, q * QBK);
  for (unsigned hhalf = 0; hhalf < 2; ++hhalf)
    k_final<<<BD / TBF / 2, 256, 0, stream>>>(embeds, gfeat,
                                              Wg1, bg1, Wg2, bg2, Wg3, bg3,
                                              Wo1, bo1, Wo2, bo2, Wo3, bo3,
                                              outp, hhalf * (BD / TBF / 2));
}

// Round 20
// 428.971 us; speedup vs baseline: 1.9185x; 1.1188x over previous
//
#include <hip/hip_runtime.h>

// Problem constants
#define BD   32768
#define NPG  54
#define NN   (BD * NPG)          // 1,769,472 nodes
#define NE   (BD * 144)          // 4,718,592 edges
#define DIN  16
#define DH   32
#define GLOBF 16
#define TBF  32                  // boards per final block
#define RB   256                 // nodes per dst bucket
#define NBK  (NN / RB)           // 6912 buckets
#define SRCM 0x1FFFFFu           // 21-bit src mask
#define CH1  256                 // conv1 sort-chunk (1 rec/thread)
#define CH2  512                 // conv2 sort-chunk
#define STW  18                  // conv1 sort-row stride (floats): 72B, b64-aligned
#define ST2  6                   // conv2 sort-row stride (floats): 24B, b64-aligned
#define HB   256                 // hist blocks
#define EB   4096                // edges per place block
#define NBA  (NE / EB)           // 1152
#define NCL  108                 // classes = d>>14 (64 buckets each)
#define CPB  12                  // placeB chunks per class

// ---------------------------------------------------------------------------
// Pass 1: dst-bucket histogram (LDS-staged)
// ---------------------------------------------------------------------------
__global__ __launch_bounds__(256) void k_histl(const int* __restrict__ ei,
                                               unsigned* __restrict__ hist) {
  __shared__ unsigned h[NBK];                            // 27648 B
  const int tid = threadIdx.x;
  for (int i = tid; i < NBK; i += 256) h[i] = 0u;
  __syncthreads();
  const unsigned base = blockIdx.x * (NE / HB);
  for (unsigned i = tid; i < NE / HB; i += 256u) {
    unsigned d = (unsigned)ei[NE + base + i];
    atomicAdd(&h[d >> 8], 1u);
  }
  __syncthreads();
  for (int i = tid; i < NBK; i += 256)
    if (h[i]) atomicAdd(&hist[i], h[i]);
}

// ---------------------------------------------------------------------------
// Pass 2: exclusive scan; also inits class cursors for placeA
// ---------------------------------------------------------------------------
__global__ __launch_bounds__(1024) void k_scan2(const unsigned* __restrict__ hist,
                                                unsigned* __restrict__ base,
                                                unsigned* __restrict__ cursorB,
                                                unsigned* __restrict__ curA) {
  __shared__ unsigned s[1024];
  const int tid = threadIdx.x;
  unsigned loc[7]; unsigned run = 0;
#pragma unroll
  for (int j = 0; j < 7; ++j) {
    int idx = tid * 7 + j;
    unsigned v = (idx < NBK) ? hist[idx] : 0u;
    loc[j] = run; run += v;
  }
  s[tid] = run; __syncthreads();
  for (int off = 1; off < 1024; off <<= 1) {
    unsigned t = (tid >= off) ? s[tid - off] : 0u;
    __syncthreads(); s[tid] += t; __syncthreads();
  }
  unsigned cb = tid ? s[tid - 1] : 0u;
#pragma unroll
  for (int j = 0; j < 7; ++j) {
    int idx = tid * 7 + j;
    if (idx < NBK) {
      unsigned b = cb + loc[j];
      base[idx] = b; cursorB[idx] = b;
      if ((idx & 63) == 0) curA[idx >> 6] = b;
    }
  }
  if (tid == 1023) base[NBK] = s[1023];                  // = NE
}

// ---------------------------------------------------------------------------
// placeA: LDS counting sort of 4096 edges by class (d>>14), run-claim flush
// ---------------------------------------------------------------------------
__global__ __launch_bounds__(256) void k_placeA(
    const int* __restrict__ ei, const float* __restrict__ ea,
    unsigned* __restrict__ curA, uint2* __restrict__ recA,
    unsigned char* __restrict__ dhiA) {
  __shared__ uint2 buf[EB];                              // 32768 B
  __shared__ unsigned char cls8[EB];                     // 4096 B
  __shared__ unsigned char dh6[EB];                      // 4096 B
  __shared__ unsigned h[NCL];
  __shared__ unsigned sb[NCL];
  __shared__ unsigned posL[NCL];
  const int tid = threadIdx.x;
  const unsigned eb = blockIdx.x * (unsigned)EB;

  for (int k = tid; k < NCL; k += 256) h[k] = 0u;
  __syncthreads();

  unsigned rkcls[16];                                    // rank(12b) | class<<12
#pragma unroll
  for (int i = 0; i < 16; ++i) {
    unsigned e = eb + i * 256u + tid;
    unsigned d = (unsigned)ei[NE + e];
    unsigned c = d >> 14;
    unsigned rk = atomicAdd(&h[c], 1u);
    rkcls[i] = rk | (c << 12);
  }
  __syncthreads();
  if (tid == 0) {
    unsigned runl = 0;
    for (int k = 0; k < NCL; ++k) { sb[k] = runl; runl += h[k]; }
  }
  __syncthreads();
  if (tid < NCL) posL[tid] = atomicAdd(&curA[tid], h[tid]);
  __syncthreads();

#pragma unroll
  for (int i = 0; i < 16; ++i) {
    unsigned e = eb + i * 256u + tid;
    unsigned sv = (unsigned)ei[e];
    unsigned d  = (unsigned)ei[NE + e];
    float    w  = ea[e];
    unsigned c  = rkcls[i] >> 12;
    unsigned slot = sb[c] + (rkcls[i] & 0xFFFu);
    buf[slot]  = make_uint2(sv | ((d & 255u) << 21), __float_as_uint(w));
    cls8[slot] = (unsigned char)c;
    dh6[slot]  = (unsigned char)((d >> 8) & 63u);
  }
  __syncthreads();

  for (int i = tid; i < EB; i += 256) {
    unsigned c = cls8[i];
    unsigned pos = posL[c] + (unsigned)i - sb[c];
    recA[pos] = buf[i];
    dhiA[pos] = dh6[i];
  }
}

// ---------------------------------------------------------------------------
// placeB: within class, sort 4096-record chunk by bucket-in-class, run-claims
// ---------------------------------------------------------------------------
__global__ __launch_bounds__(256) void k_placeB(
    const uint2* __restrict__ recA, const unsigned char* __restrict__ dhiA,
    const unsigned* __restrict__ base, unsigned* __restrict__ curB,
    uint2* __restrict__ rec) {
  __shared__ uint2 buf[EB];                              // 32768 B
  __shared__ unsigned char dh6[EB];                      // 4096 B
  __shared__ unsigned h[64];
  __shared__ unsigned sb[64];
  __shared__ unsigned posL[64];
  const int tid = threadIdx.x;
  const unsigned c = blockIdx.x / CPB;
  const unsigned j = blockIdx.x % CPB;
  const unsigned clsLo = base[c * 64];
  const unsigned clsHi = base[c * 64 + 64];
  const unsigned lo = clsLo + j * (unsigned)EB;
  if (lo >= clsHi) return;
  const unsigned hi = min(lo + (unsigned)EB, clsHi);
  const unsigned cnt = hi - lo;

  if (tid < 64) h[tid] = 0u;
  __syncthreads();

  unsigned rkd[16];
#pragma unroll
  for (int i = 0; i < 16; ++i) {
    unsigned idx = lo + i * 256u + tid;
    rkd[i] = 0xFFFFFFFFu;
    if (idx < hi) {
      unsigned dh = dhiA[idx];
      unsigned rk = atomicAdd(&h[dh], 1u);
      rkd[i] = rk | (dh << 12);
    }
  }
  __syncthreads();
  if (tid == 0) {
    unsigned runl = 0;
    for (int k = 0; k < 64; ++k) { sb[k] = runl; runl += h[k]; }
  }
  __syncthreads();
  if (tid < 64) posL[tid] = atomicAdd(&curB[c * 64u + tid], h[tid]);
  __syncthreads();

#pragma unroll
  for (int i = 0; i < 16; ++i) {
    if (rkd[i] != 0xFFFFFFFFu) {
      unsigned idx = lo + i * 256u + tid;
      unsigned dh = rkd[i] >> 12;
      unsigned slot = sb[dh] + (rkd[i] & 0xFFFu);
      buf[slot] = recA[idx];
      dh6[slot] = (unsigned char)dh;
    }
  }
  __syncthreads();

  for (unsigned i = tid; i < cnt; i += 256) {
    unsigned k = dh6[i];
    unsigned pos = posL[k] + i - sb[k];
    rec[pos] = buf[i];
  }
}

// shfl-based exclusive scan helper (256 threads, packed 16+16 fields)
__device__ __forceinline__ unsigned block_excl_scan_packed(
    unsigned packed, unsigned* wsum, int tid) {
  unsigned v = packed;
#pragma unroll
  for (int off = 1; off < 64; off <<= 1) {
    unsigned t = __shfl_up(v, off, 64);
    if ((tid & 63) >= off) v += t;
  }
  if ((tid & 63) == 63) wsum[tid >> 6] = v;
  __syncthreads();
  const int wid = tid >> 6;
  unsigned wpre = 0;
#pragma unroll
  for (int wmid = 0; wmid < 4; ++wmid)
    if (wmid < wid) wpre += wsum[wmid];
  return v + wpre - packed;            // exclusive
}

// ---------------------------------------------------------------------------
// Conv1 (dual counting sort; CH1=256, 1 rec/thread) -> z2, r2  [single launch]
// ---------------------------------------------------------------------------
__global__ __launch_bounds__(256) void k_conv1s(
    const uint2* __restrict__ rec, const unsigned* __restrict__ base,
    const float* __restrict__ x,
    const float* __restrict__ W1_rel, const float* __restrict__ b1,
    const float* __restrict__ W1_root,
    const float* __restrict__ W2_rel, const float* __restrict__ b2,
    const float* __restrict__ W2_root,
    float* __restrict__ z2, float* __restrict__ r2) {
  __shared__ float buf[CH1 * STW];       // 18432 B
  __shared__ uint2 prm[CH1];             // 2048 B
  __shared__ unsigned hd[256];
  __shared__ unsigned hs[256];
  __shared__ unsigned sc[256];
  __shared__ unsigned wsum[4];
  const int tid = threadIdx.x;
  const unsigned bk = blockIdx.x;
  const unsigned r0 = base[bk], r1 = base[bk + 1];

  float a[16];
#pragma unroll
  for (int i = 0; i < 16; ++i) a[i] = 0.f;

  for (unsigned c0 = r0; c0 < r1; c0 += CH1) {
    const unsigned validCnt = min((unsigned)CH1, r1 - c0);
    hd[tid] = 0u; hs[tid] = 0u;
    __syncthreads();

    const unsigned i0 = c0 + tid;
    const bool qa = i0 < r1;
    unsigned srcA = 0, la = 0, sa = 0, wa = 0, rkda = 0, rksa = 0;
    if (qa) {
      uint2 ra = rec[i0];
      srcA = ra.x & SRCM; la = ra.x >> 21; sa = srcA >> 13; wa = ra.y;
      rkda = atomicAdd(&hd[la], 1u); rksa = atomicAdd(&hs[sa], 1u);
    }
    __syncthreads();

    const unsigned cd = hd[tid];
    const unsigned packed = cd | (hs[tid] << 16);
    const unsigned exclP = block_excl_scan_packed(packed, wsum, tid);
    const unsigned myoff = exclP & 0xffffu;
    sc[tid] = exclP;
    __syncthreads();

    if (qa) {
      unsigned dslot = (sc[la] & 0xffffu) + rkda;
      unsigned spos  = (sc[sa] >> 16) + rksa;
      prm[spos] = make_uint2(srcA | (dslot << 21), wa);
    }
    __syncthreads();

    // gather phase in ascending-src order; scatter as 8x float2 (b64)
    if (tid < (int)validCnt) {
      uint2 pa = prm[tid];
      const float4* xp = reinterpret_cast<const float4*>(x + (size_t)(pa.x & SRCM) * 16);
      float4 xa0 = xp[0], xa1 = xp[1], xa2 = xp[2], xa3 = xp[3];
      float w = __uint_as_float(pa.y);
      float2* bp2 = reinterpret_cast<float2*>(buf + (size_t)(pa.x >> 21) * STW);
      bp2[0] = make_float2(xa0.x*w, xa0.y*w);
      bp2[1] = make_float2(xa0.z*w, xa0.w*w);
      bp2[2] = make_float2(xa1.x*w, xa1.y*w);
      bp2[3] = make_float2(xa1.z*w, xa1.w*w);
      bp2[4] = make_float2(xa2.x*w, xa2.y*w);
      bp2[5] = make_float2(xa2.z*w, xa2.w*w);
      bp2[6] = make_float2(xa3.x*w, xa3.y*w);
      bp2[7] = make_float2(xa3.z*w, xa3.w*w);
    }
    __syncthreads();

    for (unsigned k = 0; k < cd; ++k) {
      const float2* bp2 = reinterpret_cast<const float2*>(buf + (size_t)(myoff + k) * STW);
      float2 m0 = bp2[0], m1 = bp2[1], m2 = bp2[2], m3 = bp2[3];
      float2 m4 = bp2[4], m5 = bp2[5], m6 = bp2[6], m7 = bp2[7];
      a[0]  += m0.x; a[1]  += m0.y; a[2]  += m1.x; a[3]  += m1.y;
      a[4]  += m2.x; a[5]  += m2.y; a[6]  += m3.x; a[7]  += m3.y;
      a[8]  += m4.x; a[9]  += m4.y; a[10] += m5.x; a[11] += m5.y;
      a[12] += m6.x; a[13] += m6.y; a[14] += m7.x; a[15] += m7.y;
    }
    __syncthreads();
  }

  size_t n = (size_t)bk * RB + tid;
  float xv[16];
  {
    const float4* xp = reinterpret_cast<const float4*>(x + n * 16);
#pragma unroll
    for (int q = 0; q < 4; ++q) {
      float4 t2 = xp[q];
      xv[4*q+0] = t2.x; xv[4*q+1] = t2.y; xv[4*q+2] = t2.z; xv[4*q+3] = t2.w;
    }
  }
  float h[DH];
#pragma unroll
  for (int j = 0; j < DH; ++j) h[j] = b1[j];
#pragma unroll
  for (int i = 0; i < DIN; ++i) {
    float ai = a[i], xi = xv[i];
#pragma unroll
    for (int j = 0; j < DH; ++j)
      h[j] = fmaf(ai, W1_rel[i * DH + j], fmaf(xi, W1_root[i * DH + j], h[j]));
  }
#pragma unroll
  for (int j = 0; j < DH; ++j) h[j] = fmaxf(h[j], 0.f);
  float z[4] = {0.f, 0.f, 0.f, 0.f};
  float r[4] = {b2[0], b2[1], b2[2], b2[3]};
#pragma unroll
  for (int j = 0; j < DH; ++j) {
    float hj = h[j];
#pragma unroll
    for (int k = 0; k < 4; ++k) {
      z[k] = fmaf(hj, W2_rel[j * 4 + k], z[k]);
      r[k] = fmaf(hj, W2_root[j * 4 + k], r[k]);
    }
  }
  *reinterpret_cast<float4*>(z2 + n * 4) = make_float4(z[0], z[1], z[2], z[3]);
  *reinterpret_cast<float4*>(r2 + n * 4) = make_float4(r[0], r[1], r[2], r[3]);
}

// ---------------------------------------------------------------------------
// Conv2 (dual counting sort; CH2=512, ST2=6)  [single launch]
// ---------------------------------------------------------------------------
__global__ __launch_bounds__(256) void k_conv2s(
    const uint2* __restrict__ rec, const unsigned* __restrict__ base,
    const float* __restrict__ z2, const float* __restrict__ r2,
    float* __restrict__ embeds) {
  __shared__ float buf[CH2 * ST2];       // 12288 B
  __shared__ uint2 prm[CH2];
  __shared__ unsigned hd[256];
  __shared__ unsigned hs[256];
  __shared__ unsigned sc[256];
  __shared__ unsigned wsum[4];
  const int tid = threadIdx.x;
  const unsigned bk = blockIdx.x;
  const unsigned r0 = base[bk], r1 = base[bk + 1];

  float4 a = make_float4(0.f, 0.f, 0.f, 0.f);

  for (unsigned c0 = r0; c0 < r1; c0 += CH2) {
    const unsigned validCnt = min((unsigned)CH2, r1 - c0);
    hd[tid] = 0u; hs[tid] = 0u;
    __syncthreads();

    const unsigned i0 = c0 + tid;
    const unsigned i1 = c0 + 256u + tid;
    const bool qa = i0 < r1;
    const bool qb = i1 < r1;
    unsigned srcA = 0, srcB = 0, la = 0, lb = 0, sa = 0, sb2 = 0;
    unsigned wa = 0, wb = 0, rkda = 0, rkdb = 0, rksa = 0, rksb = 0;
    if (qa) {
      uint2 ra = rec[i0];
      srcA = ra.x & SRCM; la = ra.x >> 21; sa = srcA >> 13; wa = ra.y;
    }
    if (qb) {
      uint2 rb = rec[i1];
      srcB = rb.x & SRCM; lb = rb.x >> 21; sb2 = srcB >> 13; wb = rb.y;
    }
    if (qa) { rkda = atomicAdd(&hd[la], 1u); rksa = atomicAdd(&hs[sa], 1u); }
    if (qb) { rkdb = atomicAdd(&hd[lb], 1u); rksb = atomicAdd(&hs[sb2], 1u); }
    __syncthreads();

    const unsigned cd = hd[tid];
    const unsigned packed = cd | (hs[tid] << 16);
    const unsigned exclP = block_excl_scan_packed(packed, wsum, tid);
    const unsigned myoff = exclP & 0xffffu;
    sc[tid] = exclP;
    __syncthreads();

    if (qa) {
      unsigned dslot = (sc[la] & 0xffffu) + rkda;
      unsigned spos  = (sc[sa] >> 16) + rksa;
      prm[spos] = make_uint2(srcA | (dslot << 21), wa);
    }
    if (qb) {
      unsigned dslot = (sc[lb] & 0xffffu) + rkdb;
      unsigned spos  = (sc[sb2] >> 16) + rksb;
      prm[spos] = make_uint2(srcB | (dslot << 21), wb);
    }
    __syncthreads();

    {
      const bool ga = tid < validCnt;
      const bool gb = tid + 256u < validCnt;
      uint2 pa, pb;
      float4 za, zb;
      if (ga) {
        pa = prm[tid];
        za = *reinterpret_cast<const float4*>(z2 + (size_t)(pa.x & SRCM) * 4);
      }
      if (gb) {
        pb = prm[tid + 256];
        zb = *reinterpret_cast<const float4*>(z2 + (size_t)(pb.x & SRCM) * 4);
      }
      if (ga) {
        float w = __uint_as_float(pa.y);
        float2* bp2 = reinterpret_cast<float2*>(buf + (size_t)(pa.x >> 21) * ST2);
        bp2[0] = make_float2(za.x*w, za.y*w);
        bp2[1] = make_float2(za.z*w, za.w*w);
      }
      if (gb) {
        float w = __uint_as_float(pb.y);
        float2* bp2 = reinterpret_cast<float2*>(buf + (size_t)(pb.x >> 21) * ST2);
        bp2[0] = make_float2(zb.x*w, zb.y*w);
        bp2[1] = make_float2(zb.z*w, zb.w*w);
      }
    }
    __syncthreads();

    for (unsigned k = 0; k < cd; ++k) {
      const float2* bp2 = reinterpret_cast<const float2*>(buf + (size_t)(myoff + k) * ST2);
      float2 m0 = bp2[0], m1 = bp2[1];
      a.x += m0.x; a.y += m0.y; a.z += m1.x; a.w += m1.y;
    }
    __syncthreads();
  }

  size_t n = (size_t)bk * RB + tid;
  const float4 rr = *reinterpret_cast<const float4*>(r2 + n * 4);
  float4 o;
  o.x = fmaxf(a.x + rr.x, 0.f);
  o.y = fmaxf(a.y + rr.y, 0.f);
  o.z = fmaxf(a.z + rr.z, 0.f);
  o.w = fmaxf(a.w + rr.w, 0.f);
  *reinterpret_cast<float4*>(embeds + n * 4) = o;
}

// ---------------------------------------------------------------------------
// Final MLP (single full-grid launch)
// ---------------------------------------------------------------------------
__global__ __launch_bounds__(256, 2) void k_final(
    const float* __restrict__ embeds, const float* __restrict__ gfeat,
    const float* __restrict__ Wg1, const float* __restrict__ bg1,
    const float* __restrict__ Wg2, const float* __restrict__ bg2,
    const float* __restrict__ Wg3, const float* __restrict__ bg3,
    const float* __restrict__ Wo1, const float* __restrict__ bo1,
    const float* __restrict__ Wo2, const float* __restrict__ bo2,
    const float* __restrict__ Wo3, const float* __restrict__ bo3,
    float* __restrict__ out) {
  __shared__ float svec[TBF * 232];
  __shared__ float sbuf1[TBF * 128];
  float* sbuf2 = svec;

  const int tid = threadIdx.x;
  const int b0  = blockIdx.x * TBF;

  {
    const float4* src = reinterpret_cast<const float4*>(embeds + (size_t)b0 * 216);
    for (int f4i = tid; f4i < TBF * 54; f4i += 256) {
      int b = f4i / 54;
      int k4 = f4i - b * 54;
      *reinterpret_cast<float4*>(svec + b * 232 + k4 * 4) = src[f4i];
    }
  }
  if (tid < TBF) {
    const float* gf = gfeat + (size_t)(b0 + tid) * GLOBF;
    float gin[16];
#pragma unroll
    for (int i = 0; i < 16; ++i) gin[i] = gf[i];
    float g1[8];
#pragma unroll
    for (int j = 0; j < 8; ++j) {
      float acc = bg1[j];
#pragma unroll
      for (int i = 0; i < 16; ++i) acc = fmaf(gin[i], Wg1[i * 8 + j], acc);
      g1[j] = fmaxf(acc, 0.f);
    }
    float g2[8];
#pragma unroll
    for (int j = 0; j < 8; ++j) {
      float acc = bg2[j];
#pragma unroll
      for (int i = 0; i < 8; ++i) acc = fmaf(g1[i], Wg2[i * 8 + j], acc);
      g2[j] = fmaxf(acc, 0.f);
    }
#pragma unroll
    for (int j = 0; j < 16; ++j) {
      float acc = bg3[j];
#pragma unroll
      for (int i = 0; i < 8; ++i) acc = fmaf(g2[i], Wg3[i * 16 + j], acc);
      svec[tid * 232 + 216 + j] = fmaxf(acc, 0.f);
    }
  }
  __syncthreads();

  const int c0 = (tid & 31) * 4;
  const int rb = (tid >> 5) * 4;

  {
    const float* Wp = Wo1 + c0;
    float4 w0 = *reinterpret_cast<const float4*>(Wp + 0 * 128);
    float4 w1 = *reinterpret_cast<const float4*>(Wp + 1 * 128);
    float4 w2 = *reinterpret_cast<const float4*>(Wp + 2 * 128);
    float4 w3 = *reinterpret_cast<const float4*>(Wp + 3 * 128);
    float acc[4][4];
#pragma unroll
    for (int r = 0; r < 4; ++r)
#pragma unroll
      for (int c = 0; c < 4; ++c) acc[r][c] = 0.f;
    for (int i4 = 0; i4 < 58; ++i4) {
      float4 n0, n1, n2, n3;
      if (i4 < 57) {
        const float* Np = Wp + (size_t)(i4 * 4 + 4) * 128;
        n0 = *reinterpret_cast<const float4*>(Np + 0 * 128);
        n1 = *reinterpret_cast<const float4*>(Np + 1 * 128);
        n2 = *reinterpret_cast<const float4*>(Np + 2 * 128);
        n3 = *reinterpret_cast<const float4*>(Np + 3 * 128);
      }
#pragma unroll
      for (int r = 0; r < 4; ++r) {
        const float4 s = *reinterpret_cast<const float4*>(svec + (rb+r)*232 + i4*4);
        acc[r][0] = fmaf(s.x, w0.x, fmaf(s.y, w1.x, fmaf(s.z, w2.x, fmaf(s.w, w3.x, acc[r][0]))));
        acc[r][1] = fmaf(s.x, w0.y, fmaf(s.y, w1.y, fmaf(s.z, w2.y, fmaf(s.w, w3.y, acc[r][1]))));
        acc[r][2] = fmaf(s.x, w0.z, fmaf(s.y, w1.z, fmaf(s.z, w2.z, fmaf(s.w, w3.z, acc[r][2]))));
        acc[r][3] = fmaf(s.x, w0.w, fmaf(s.y, w1.w, fmaf(s.z, w2.w, fmaf(s.w, w3.w, acc[r][3]))));
      }
      w0 = n0; w1 = n1; w2 = n2; w3 = n3;
    }
    const float4 bv = *reinterpret_cast<const float4*>(bo1 + c0);
#pragma unroll
    for (int r = 0; r < 4; ++r) {
      float4 o;
      o.x = fmaxf(acc[r][0] + bv.x, 0.f);
      o.y = fmaxf(acc[r][1] + bv.y, 0.f);
      o.z = fmaxf(acc[r][2] + bv.z, 0.f);
      o.w = fmaxf(acc[r][3] + bv.w, 0.f);
      *reinterpret_cast<float4*>(sbuf1 + (rb + r) * 128 + c0) = o;
    }
  }
  __syncthreads();

  {
    const float* Wp = Wo2 + c0;
    float4 w0 = *reinterpret_cast<const float4*>(Wp + 0 * 128);
    float4 w1 = *reinterpret_cast<const float4*>(Wp + 1 * 128);
    float4 w2 = *reinterpret_cast<const float4*>(Wp + 2 * 128);
    float4 w3 = *reinterpret_cast<const float4*>(Wp + 3 * 128);
    float acc[4][4];
#pragma unroll
    for (int r = 0; r < 4; ++r)
#pragma unroll
      for (int c = 0; c < 4; ++c) acc[r][c] = 0.f;
    for (int i4 = 0; i4 < 32; ++i4) {
      float4 n0, n1, n2, n3;
      if (i4 < 31) {
        const float* Np = Wp + (size_t)(i4 * 4 + 4) * 128;
        n0 = *reinterpret_cast<const float4*>(Np + 0 * 128);
        n1 = *reinterpret_cast<const float4*>(Np + 1 * 128);
        n2 = *reinterpret_cast<const float4*>(Np + 2 * 128);
        n3 = *reinterpret_cast<const float4*>(Np + 3 * 128);
      }
#pragma unroll
      for (int r = 0; r < 4; ++r) {
        const float4 s = *reinterpret_cast<const float4*>(sbuf1 + (rb+r)*128 + i4*4);
        acc[r][0] = fmaf(s.x, w0.x, fmaf(s.y, w1.x, fmaf(s.z, w2.x, fmaf(s.w, w3.x, acc[r][0]))));
        acc[r][1] = fmaf(s.x, w0.y, fmaf(s.y, w1.y, fmaf(s.z, w2.y, fmaf(s.w, w3.y, acc[r][1]))));
        acc[r][2] = fmaf(s.x, w0.z, fmaf(s.y, w1.z, fmaf(s.z, w2.z, fmaf(s.w, w3.z, acc[r][2]))));
        acc[r][3] = fmaf(s.x, w0.w, fmaf(s.y, w1.w, fmaf(s.z, w2.w, fmaf(s.w, w3.w, acc[r][3]))));
      }
      w0 = n0; w1 = n1; w2 = n2; w3 = n3;
    }
    const float4 bv = *reinterpret_cast<const float4*>(bo2 + c0);
#pragma unroll
    for (int r = 0; r < 4; ++r) {
      float4 o;
      o.x = fmaxf(acc[r][0] + bv.x, 0.f);
      o.y = fmaxf(acc[r][1] + bv.y, 0.f);
      o.z = fmaxf(acc[r][2] + bv.z, 0.f);
      o.w = fmaxf(acc[r][3] + bv.w, 0.f);
      *reinterpret_cast<float4*>(sbuf2 + (rb + r) * 128 + c0) = o;
    }
  }
  __syncthreads();

  {
    const int c2 = (tid & 31) * 2;
    const float* Wp = Wo3 + c2;
    float2 w0 = *reinterpret_cast<const float2*>(Wp + 0 * 64);
    float2 w1 = *reinterpret_cast<const float2*>(Wp + 1 * 64);
    float2 w2 = *reinterpret_cast<const float2*>(Wp + 2 * 64);
    float2 w3 = *reinterpret_cast<const float2*>(Wp + 3 * 64);
    float acc[4][2];
#pragma unroll
    for (int r = 0; r < 4; ++r) { acc[r][0] = 0.f; acc[r][1] = 0.f; }
    for (int i4 = 0; i4 < 32; ++i4) {
      float2 n0, n1, n2, n3;
      if (i4 < 31) {
        const float* Np = Wp + (size_t)(i4 * 4 + 4) * 64;
        n0 = *reinterpret_cast<const float2*>(Np + 0 * 64);
        n1 = *reinterpret_cast<const float2*>(Np + 1 * 64);
        n2 = *reinterpret_cast<const float2*>(Np + 2 * 64);
        n3 = *reinterpret_cast<const float2*>(Np + 3 * 64);
      }
#pragma unroll
      for (int r = 0; r < 4; ++r) {
        const float4 s = *reinterpret_cast<const float4*>(sbuf2 + (rb+r)*128 + i4*4);
        acc[r][0] = fmaf(s.x, w0.x, fmaf(s.y, w1.x, fmaf(s.z, w2.x, fmaf(s.w, w3.x, acc[r][0]))));
        acc[r][1] = fmaf(s.x, w0.y, fmaf(s.y, w1.y, fmaf(s.z, w2.y, fmaf(s.w, w3.y, acc[r][1]))));
      }
      w0 = n0; w1 = n1; w2 = n2; w3 = n3;
    }
    const float2 bv = *reinterpret_cast<const float2*>(bo3 + c2);
#pragma unroll
    for (int r = 0; r < 4; ++r) {
      float2 o;
      o.x = acc[r][0] + bv.x;
      o.y = acc[r][1] + bv.y;
      *reinterpret_cast<float2*>(out + (size_t)(b0 + rb + r) * 64 + c2) = o;
    }
  }
}

// ---------------------------------------------------------------------------
extern "C" void kernel_launch(void* const* d_in, const int* in_sizes, int n_in,
                              void* d_out, int out_size, void* d_ws, size_t ws_size,
                              hipStream_t stream) {
  const float* x      = (const float*)d_in[0];
  const int*   ei     = (const int*)d_in[1];
  const float* ea     = (const float*)d_in[2];
  const float* gfeat  = (const float*)d_in[3];
  const float* W1_rel = (const float*)d_in[5];
  const float* b1     = (const float*)d_in[6];
  const float* W1_root= (const float*)d_in[7];
  const float* W2_rel = (const float*)d_in[8];
  const float* b2     = (const float*)d_in[9];
  const float* W2_root= (const float*)d_in[10];
  const float* Wg1 = (const float*)d_in[11];
  const float* bg1 = (const float*)d_in[12];
  const float* Wg2 = (const float*)d_in[13];
  const float* bg2 = (const float*)d_in[14];
  const float* Wg3 = (const float*)d_in[15];
  const float* bg3 = (const float*)d_in[16];
  const float* Wo1 = (const float*)d_in[17];
  const float* bo1 = (const float*)d_in[18];
  const float* Wo2 = (const float*)d_in[19];
  const float* bo2 = (const float*)d_in[20];
  const float* Wo3 = (const float*)d_in[21];
  const float* bo3 = (const float*)d_in[22];
  float* outp = (float*)d_out;

  // workspace (~166 MB)
  uint2*    rec    = (uint2*)d_ws;                         // NE*8B
  uint2*    recA   = rec + NE;                             // NE*8B
  unsigned char* dhiA = (unsigned char*)(recA + NE);       // NE*1B
  float*    z2     = (float*)(dhiA + NE);                  // NN*4 f
  float*    r2     = z2 + (size_t)NN * 4;                  // NN*4 f
  float*    embeds = r2 + (size_t)NN * 4;                  // NN*4 f
  unsigned* hist   = (unsigned*)(embeds + (size_t)NN * 4); // NBK
  unsigned* base   = hist + NBK;                           // NBK+1
  unsigned* cursorB= base + NBK + 1;                       // NBK
  unsigned* curA   = cursorB + NBK;                        // NCL

  hipMemsetAsync(hist, 0, NBK * sizeof(unsigned), stream);
  k_histl <<<HB, 256, 0, stream>>>(ei, hist);
  k_scan2 <<<1, 1024, 0, stream>>>(hist, base, cursorB, curA);
  k_placeA<<<NBA, 256, 0, stream>>>(ei, ea, curA, recA, dhiA);
  k_placeB<<<NCL * CPB, 256, 0, stream>>>(recA, dhiA, base, cursorB, rec);
  k_conv1s<<<NBK, 256, 0, stream>>>(rec, base, x, W1_rel, b1, W1_root,
                                    W2_rel, b2, W2_root, z2, r2);
  k_conv2s<<<NBK, 256, 0, stream>>>(rec, base, z2, r2, embeds);
  k_final <<<BD / TBF, 256, 0, stream>>>(embeds, gfeat,
                                         Wg1, bg1, Wg2, bg2, Wg3, bg3,
                                         Wo1, bo1, Wo2, bo2, Wo3, bo3, outp);
}

// Round 21
// 428.018 us; speedup vs baseline: 1.9227x; 1.0022x over previous
//
#include <hip/hip_runtime.h>

// Problem constants
#define BD   32768
#define NPG  54
#define NN   (BD * NPG)          // 1,769,472 nodes
#define NE   (BD * 144)          // 4,718,592 edges
#define DIN  16
#define DH   32
#define GLOBF 16
#define TBF  32                  // boards per final block
#define RB   256                 // nodes per dst bucket
#define NBK  (NN / RB)           // 6912 buckets
#define SRCM 0x1FFFFFu           // 21-bit src mask
#define CH1  256                 // conv1 sort-chunk (1 rec/thread)
#define CH2  512                 // conv2 sort-chunk
#define STW  16                  // conv1 sort-row stride (floats): 64B + XOR swizzle
#define ST2  6                   // conv2 sort-row stride (floats): 24B, b64-aligned
#define HB   256                 // hist blocks
#define EB   4096                // edges per place block
#define NBA  (NE / EB)           // 1152
#define NCL  108                 // classes = d>>14 (64 buckets each)
#define CPB  12                  // placeB chunks per class

// ---------------------------------------------------------------------------
// Pass 1: dst-bucket histogram (LDS-staged)
// ---------------------------------------------------------------------------
__global__ __launch_bounds__(256) void k_histl(const int* __restrict__ ei,
                                               unsigned* __restrict__ hist) {
  __shared__ unsigned h[NBK];                            // 27648 B
  const int tid = threadIdx.x;
  for (int i = tid; i < NBK; i += 256) h[i] = 0u;
  __syncthreads();
  const unsigned base = blockIdx.x * (NE / HB);
  for (unsigned i = tid; i < NE / HB; i += 256u) {
    unsigned d = (unsigned)ei[NE + base + i];
    atomicAdd(&h[d >> 8], 1u);
  }
  __syncthreads();
  for (int i = tid; i < NBK; i += 256)
    if (h[i]) atomicAdd(&hist[i], h[i]);
}

// ---------------------------------------------------------------------------
// Pass 2: exclusive scan; also inits class cursors for placeA
// ---------------------------------------------------------------------------
__global__ __launch_bounds__(1024) void k_scan2(const unsigned* __restrict__ hist,
                                                unsigned* __restrict__ base,
                                                unsigned* __restrict__ cursorB,
                                                unsigned* __restrict__ curA) {
  __shared__ unsigned s[1024];
  const int tid = threadIdx.x;
  unsigned loc[7]; unsigned run = 0;
#pragma unroll
  for (int j = 0; j < 7; ++j) {
    int idx = tid * 7 + j;
    unsigned v = (idx < NBK) ? hist[idx] : 0u;
    loc[j] = run; run += v;
  }
  s[tid] = run; __syncthreads();
  for (int off = 1; off < 1024; off <<= 1) {
    unsigned t = (tid >= off) ? s[tid - off] : 0u;
    __syncthreads(); s[tid] += t; __syncthreads();
  }
  unsigned cb = tid ? s[tid - 1] : 0u;
#pragma unroll
  for (int j = 0; j < 7; ++j) {
    int idx = tid * 7 + j;
    if (idx < NBK) {
      unsigned b = cb + loc[j];
      base[idx] = b; cursorB[idx] = b;
      if ((idx & 63) == 0) curA[idx >> 6] = b;
    }
  }
  if (tid == 1023) base[NBK] = s[1023];                  // = NE
}

// ---------------------------------------------------------------------------
// placeA: LDS counting sort of 4096 edges by class (d>>14), run-claim flush
// ---------------------------------------------------------------------------
__global__ __launch_bounds__(256) void k_placeA(
    const int* __restrict__ ei, const float* __restrict__ ea,
    unsigned* __restrict__ curA, uint2* __restrict__ recA,
    unsigned char* __restrict__ dhiA) {
  __shared__ uint2 buf[EB];                              // 32768 B
  __shared__ unsigned char cls8[EB];                     // 4096 B
  __shared__ unsigned char dh6[EB];                      // 4096 B
  __shared__ unsigned h[NCL];
  __shared__ unsigned sb[NCL];
  __shared__ unsigned posL[NCL];
  const int tid = threadIdx.x;
  const unsigned eb = blockIdx.x * (unsigned)EB;

  for (int k = tid; k < NCL; k += 256) h[k] = 0u;
  __syncthreads();

  unsigned rkcls[16];                                    // rank(12b) | class<<12
#pragma unroll
  for (int i = 0; i < 16; ++i) {
    unsigned e = eb + i * 256u + tid;
    unsigned d = (unsigned)ei[NE + e];
    unsigned c = d >> 14;
    unsigned rk = atomicAdd(&h[c], 1u);
    rkcls[i] = rk | (c << 12);
  }
  __syncthreads();
  if (tid == 0) {
    unsigned runl = 0;
    for (int k = 0; k < NCL; ++k) { sb[k] = runl; runl += h[k]; }
  }
  __syncthreads();
  if (tid < NCL) posL[tid] = atomicAdd(&curA[tid], h[tid]);
  __syncthreads();

#pragma unroll
  for (int i = 0; i < 16; ++i) {
    unsigned e = eb + i * 256u + tid;
    unsigned sv = (unsigned)ei[e];
    unsigned d  = (unsigned)ei[NE + e];
    float    w  = ea[e];
    unsigned c  = rkcls[i] >> 12;
    unsigned slot = sb[c] + (rkcls[i] & 0xFFFu);
    buf[slot]  = make_uint2(sv | ((d & 255u) << 21), __float_as_uint(w));
    cls8[slot] = (unsigned char)c;
    dh6[slot]  = (unsigned char)((d >> 8) & 63u);
  }
  __syncthreads();

  for (int i = tid; i < EB; i += 256) {
    unsigned c = cls8[i];
    unsigned pos = posL[c] + (unsigned)i - sb[c];
    recA[pos] = buf[i];
    dhiA[pos] = dh6[i];
  }
}

// ---------------------------------------------------------------------------
// placeB: within class, sort 4096-record chunk by bucket-in-class, run-claims
// ---------------------------------------------------------------------------
__global__ __launch_bounds__(256) void k_placeB(
    const uint2* __restrict__ recA, const unsigned char* __restrict__ dhiA,
    const unsigned* __restrict__ base, unsigned* __restrict__ curB,
    uint2* __restrict__ rec) {
  __shared__ uint2 buf[EB];                              // 32768 B
  __shared__ unsigned char dh6[EB];                      // 4096 B
  __shared__ unsigned h[64];
  __shared__ unsigned sb[64];
  __shared__ unsigned posL[64];
  const int tid = threadIdx.x;
  const unsigned c = blockIdx.x / CPB;
  const unsigned j = blockIdx.x % CPB;
  const unsigned clsLo = base[c * 64];
  const unsigned clsHi = base[c * 64 + 64];
  const unsigned lo = clsLo + j * (unsigned)EB;
  if (lo >= clsHi) return;
  const unsigned hi = min(lo + (unsigned)EB, clsHi);
  const unsigned cnt = hi - lo;

  if (tid < 64) h[tid] = 0u;
  __syncthreads();

  unsigned rkd[16];
#pragma unroll
  for (int i = 0; i < 16; ++i) {
    unsigned idx = lo + i * 256u + tid;
    rkd[i] = 0xFFFFFFFFu;
    if (idx < hi) {
      unsigned dh = dhiA[idx];
      unsigned rk = atomicAdd(&h[dh], 1u);
      rkd[i] = rk | (dh << 12);
    }
  }
  __syncthreads();
  if (tid == 0) {
    unsigned runl = 0;
    for (int k = 0; k < 64; ++k) { sb[k] = runl; runl += h[k]; }
  }
  __syncthreads();
  if (tid < 64) posL[tid] = atomicAdd(&curB[c * 64u + tid], h[tid]);
  __syncthreads();

#pragma unroll
  for (int i = 0; i < 16; ++i) {
    if (rkd[i] != 0xFFFFFFFFu) {
      unsigned idx = lo + i * 256u + tid;
      unsigned dh = rkd[i] >> 12;
      unsigned slot = sb[dh] + (rkd[i] & 0xFFFu);
      buf[slot] = recA[idx];
      dh6[slot] = (unsigned char)dh;
    }
  }
  __syncthreads();

  for (unsigned i = tid; i < cnt; i += 256) {
    unsigned k = dh6[i];
    unsigned pos = posL[k] + i - sb[k];
    rec[pos] = buf[i];
  }
}

// shfl-based exclusive scan helper (256 threads, packed 16+16 fields)
__device__ __forceinline__ unsigned block_excl_scan_packed(
    unsigned packed, unsigned* wsum, int tid) {
  unsigned v = packed;
#pragma unroll
  for (int off = 1; off < 64; off <<= 1) {
    unsigned t = __shfl_up(v, off, 64);
    if ((tid & 63) >= off) v += t;
  }
  if ((tid & 63) == 63) wsum[tid >> 6] = v;
  __syncthreads();
  const int wid = tid >> 6;
  unsigned wpre = 0;
#pragma unroll
  for (int wmid = 0; wmid < 4; ++wmid)
    if (wmid < wid) wpre += wsum[wmid];
  return v + wpre - packed;            // exclusive
}

// ---------------------------------------------------------------------------
// Conv1 (dual counting sort; LDS trimmed to exactly 20KB -> 8 blocks/CU):
//  - STW=16 rows with float2 XOR swizzle (j2 ^= (slot>>1)&7): 4-way b64 banks
//  - sc aliases hd (cd read pre-barrier, offsets written post-barrier)
//  - wsum overlays hs[252..255] (sa = src>>13 <= 215, never touches those)
// ---------------------------------------------------------------------------
__global__ __launch_bounds__(256) void k_conv1s(
    const uint2* __restrict__ rec, const unsigned* __restrict__ base,
    const float* __restrict__ x,
    const float* __restrict__ W1_rel, const float* __restrict__ b1,
    const float* __restrict__ W1_root,
    const float* __restrict__ W2_rel, const float* __restrict__ b2,
    const float* __restrict__ W2_root,
    float* __restrict__ z2, float* __restrict__ r2) {
  __shared__ float buf[CH1 * STW];       // 16384 B
  __shared__ uint2 prm[CH1];             // 2048 B
  __shared__ unsigned hd[256];           // 1024 B (doubles as sc after scan)
  __shared__ unsigned hs[256];           // 1024 B (tail [252..255] = wsum)
  unsigned* sc = hd;                     // alias
  unsigned* wsum = hs + 252;             // overlay
  const int tid = threadIdx.x;
  const unsigned bk = blockIdx.x;
  const unsigned r0 = base[bk], r1 = base[bk + 1];

  float a[16];
#pragma unroll
  for (int i = 0; i < 16; ++i) a[i] = 0.f;

  for (unsigned c0 = r0; c0 < r1; c0 += CH1) {
    const unsigned validCnt = min((unsigned)CH1, r1 - c0);
    hd[tid] = 0u; hs[tid] = 0u;
    __syncthreads();

    const unsigned i0 = c0 + tid;
    const bool qa = i0 < r1;
    unsigned srcA = 0, la = 0, sa = 0, wa = 0, rkda = 0, rksa = 0;
    if (qa) {
      uint2 ra = rec[i0];
      srcA = ra.x & SRCM; la = ra.x >> 21; sa = srcA >> 13; wa = ra.y;
      rkda = atomicAdd(&hd[la], 1u); rksa = atomicAdd(&hs[sa], 1u);
    }
    __syncthreads();

    const unsigned cd = hd[tid];                         // read BEFORE scan barrier
    const unsigned packed = cd | (hs[tid] << 16);
    const unsigned exclP = block_excl_scan_packed(packed, wsum, tid);
    const unsigned myoff = exclP & 0xffffu;
    sc[tid] = exclP;                                     // overwrite hd post-barrier
    __syncthreads();

    if (qa) {
      unsigned dslot = (sc[la] & 0xffffu) + rkda;
      unsigned spos  = (sc[sa] >> 16) + rksa;
      prm[spos] = make_uint2(srcA | (dslot << 21), wa);
    }
    __syncthreads();

    // gather in ascending-src order; scatter 8x float2 with XOR swizzle
    if (tid < (int)validCnt) {
      uint2 pa = prm[tid];
      const float4* xp = reinterpret_cast<const float4*>(x + (size_t)(pa.x & SRCM) * 16);
      float4 xa0 = xp[0], xa1 = xp[1], xa2 = xp[2], xa3 = xp[3];
      float w = __uint_as_float(pa.y);
      unsigned slot = pa.x >> 21;
      unsigned xr = (slot >> 1) & 7u;
      float2* bp2 = reinterpret_cast<float2*>(buf + (size_t)slot * STW);
      bp2[0 ^ xr] = make_float2(xa0.x*w, xa0.y*w);
      bp2[1 ^ xr] = make_float2(xa0.z*w, xa0.w*w);
      bp2[2 ^ xr] = make_float2(xa1.x*w, xa1.y*w);
      bp2[3 ^ xr] = make_float2(xa1.z*w, xa1.w*w);
      bp2[4 ^ xr] = make_float2(xa2.x*w, xa2.y*w);
      bp2[5 ^ xr] = make_float2(xa2.z*w, xa2.w*w);
      bp2[6 ^ xr] = make_float2(xa3.x*w, xa3.y*w);
      bp2[7 ^ xr] = make_float2(xa3.z*w, xa3.w*w);
    }
    __syncthreads();

    for (unsigned k = 0; k < cd; ++k) {
      const unsigned s = myoff + k;
      const unsigned xr = (s >> 1) & 7u;
      const float2* bp2 = reinterpret_cast<const float2*>(buf + (size_t)s * STW);
      float2 m0 = bp2[0 ^ xr], m1 = bp2[1 ^ xr], m2 = bp2[2 ^ xr], m3 = bp2[3 ^ xr];
      float2 m4 = bp2[4 ^ xr], m5 = bp2[5 ^ xr], m6 = bp2[6 ^ xr], m7 = bp2[7 ^ xr];
      a[0]  += m0.x; a[1]  += m0.y; a[2]  += m1.x; a[3]  += m1.y;
      a[4]  += m2.x; a[5]  += m2.y; a[6]  += m3.x; a[7]  += m3.y;
      a[8]  += m4.x; a[9]  += m4.y; a[10] += m5.x; a[11] += m5.y;
      a[12] += m6.x; a[13] += m6.y; a[14] += m7.x; a[15] += m7.y;
    }
    __syncthreads();
  }

  size_t n = (size_t)bk * RB + tid;
  float xv[16];
  {
    const float4* xp = reinterpret_cast<const float4*>(x + n * 16);
#pragma unroll
    for (int q = 0; q < 4; ++q) {
      float4 t2 = xp[q];
      xv[4*q+0] = t2.x; xv[4*q+1] = t2.y; xv[4*q+2] = t2.z; xv[4*q+3] = t2.w;
    }
  }
  float h[DH];
#pragma unroll
  for (int j = 0; j < DH; ++j) h[j] = b1[j];
#pragma unroll
  for (int i = 0; i < DIN; ++i) {
    float ai = a[i], xi = xv[i];
#pragma unroll
    for (int j = 0; j < DH; ++j)
      h[j] = fmaf(ai, W1_rel[i * DH + j], fmaf(xi, W1_root[i * DH + j], h[j]));
  }
#pragma unroll
  for (int j = 0; j < DH; ++j) h[j] = fmaxf(h[j], 0.f);
  float z[4] = {0.f, 0.f, 0.f, 0.f};
  float r[4] = {b2[0], b2[1], b2[2], b2[3]};
#pragma unroll
  for (int j = 0; j < DH; ++j) {
    float hj = h[j];
#pragma unroll
    for (int k = 0; k < 4; ++k) {
      z[k] = fmaf(hj, W2_rel[j * 4 + k], z[k]);
      r[k] = fmaf(hj, W2_root[j * 4 + k], r[k]);
    }
  }
  *reinterpret_cast<float4*>(z2 + n * 4) = make_float4(z[0], z[1], z[2], z[3]);
  *reinterpret_cast<float4*>(r2 + n * 4) = make_float4(r[0], r[1], r[2], r[3]);
}

// ---------------------------------------------------------------------------
// Conv2 (dual counting sort; CH2=512, ST2=6)  [unchanged]
// ---------------------------------------------------------------------------
__global__ __launch_bounds__(256) void k_conv2s(
    const uint2* __restrict__ rec, const unsigned* __restrict__ base,
    const float* __restrict__ z2, const float* __restrict__ r2,
    float* __restrict__ embeds) {
  __shared__ float buf[CH2 * ST2];       // 12288 B
  __shared__ uint2 prm[CH2];
  __shared__ unsigned hd[256];
  __shared__ unsigned hs[256];
  __shared__ unsigned sc[256];
  __shared__ unsigned wsum[4];
  const int tid = threadIdx.x;
  const unsigned bk = blockIdx.x;
  const unsigned r0 = base[bk], r1 = base[bk + 1];

  float4 a = make_float4(0.f, 0.f, 0.f, 0.f);

  for (unsigned c0 = r0; c0 < r1; c0 += CH2) {
    const unsigned validCnt = min((unsigned)CH2, r1 - c0);
    hd[tid] = 0u; hs[tid] = 0u;
    __syncthreads();

    const unsigned i0 = c0 + tid;
    const unsigned i1 = c0 + 256u + tid;
    const bool qa = i0 < r1;
    const bool qb = i1 < r1;
    unsigned srcA = 0, srcB = 0, la = 0, lb = 0, sa = 0, sb2 = 0;
    unsigned wa = 0, wb = 0, rkda = 0, rkdb = 0, rksa = 0, rksb = 0;
    if (qa) {
      uint2 ra = rec[i0];
      srcA = ra.x & SRCM; la = ra.x >> 21; sa = srcA >> 13; wa = ra.y;
    }
    if (qb) {
      uint2 rb = rec[i1];
      srcB = rb.x & SRCM; lb = rb.x >> 21; sb2 = srcB >> 13; wb = rb.y;
    }
    if (qa) { rkda = atomicAdd(&hd[la], 1u); rksa = atomicAdd(&hs[sa], 1u); }
    if (qb) { rkdb = atomicAdd(&hd[lb], 1u); rksb = atomicAdd(&hs[sb2], 1u); }
    __syncthreads();

    const unsigned cd = hd[tid];
    const unsigned packed = cd | (hs[tid] << 16);
    const unsigned exclP = block_excl_scan_packed(packed, wsum, tid);
    const unsigned myoff = exclP & 0xffffu;
    sc[tid] = exclP;
    __syncthreads();

    if (qa) {
      unsigned dslot = (sc[la] & 0xffffu) + rkda;
      unsigned spos  = (sc[sa] >> 16) + rksa;
      prm[spos] = make_uint2(srcA | (dslot << 21), wa);
    }
    if (qb) {
      unsigned dslot = (sc[lb] & 0xffffu) + rkdb;
      unsigned spos  = (sc[sb2] >> 16) + rksb;
      prm[spos] = make_uint2(srcB | (dslot << 21), wb);
    }
    __syncthreads();

    {
      const bool ga = tid < validCnt;
      const bool gb = tid + 256u < validCnt;
      uint2 pa, pb;
      float4 za, zb;
      if (ga) {
        pa = prm[tid];
        za = *reinterpret_cast<const float4*>(z2 + (size_t)(pa.x & SRCM) * 4);
      }
      if (gb) {
        pb = prm[tid + 256];
        zb = *reinterpret_cast<const float4*>(z2 + (size_t)(pb.x & SRCM) * 4);
      }
      if (ga) {
        float w = __uint_as_float(pa.y);
        float2* bp2 = reinterpret_cast<float2*>(buf + (size_t)(pa.x >> 21) * ST2);
        bp2[0] = make_float2(za.x*w, za.y*w);
        bp2[1] = make_float2(za.z*w, za.w*w);
      }
      if (gb) {
        float w = __uint_as_float(pb.y);
        float2* bp2 = reinterpret_cast<float2*>(buf + (size_t)(pb.x >> 21) * ST2);
        bp2[0] = make_float2(zb.x*w, zb.y*w);
        bp2[1] = make_float2(zb.z*w, zb.w*w);
      }
    }
    __syncthreads();

    for (unsigned k = 0; k < cd; ++k) {
      const float2* bp2 = reinterpret_cast<const float2*>(buf + (size_t)(myoff + k) * ST2);
      float2 m0 = bp2[0], m1 = bp2[1];
      a.x += m0.x; a.y += m0.y; a.z += m1.x; a.w += m1.y;
    }
    __syncthreads();
  }

  size_t n = (size_t)bk * RB + tid;
  const float4 rr = *reinterpret_cast<const float4*>(r2 + n * 4);
  float4 o;
  o.x = fmaxf(a.x + rr.x, 0.f);
  o.y = fmaxf(a.y + rr.y, 0.f);
  o.z = fmaxf(a.z + rr.z, 0.f);
  o.w = fmaxf(a.w + rr.w, 0.f);
  *reinterpret_cast<float4*>(embeds + n * 4) = o;
}

// ---------------------------------------------------------------------------
// Final MLP (unchanged)
// ---------------------------------------------------------------------------
__global__ __launch_bounds__(256, 2) void k_final(
    const float* __restrict__ embeds, const float* __restrict__ gfeat,
    const float* __restrict__ Wg1, const float* __restrict__ bg1,
    const float* __restrict__ Wg2, const float* __restrict__ bg2,
    const float* __restrict__ Wg3, const float* __restrict__ bg3,
    const float* __restrict__ Wo1, const float* __restrict__ bo1,
    const float* __restrict__ Wo2, const float* __restrict__ bo2,
    const float* __restrict__ Wo3, const float* __restrict__ bo3,
    float* __restrict__ out) {
  __shared__ float svec[TBF * 232];
  __shared__ float sbuf1[TBF * 128];
  float* sbuf2 = svec;

  const int tid = threadIdx.x;
  const int b0  = blockIdx.x * TBF;

  {
    const float4* src = reinterpret_cast<const float4*>(embeds + (size_t)b0 * 216);
    for (int f4i = tid; f4i < TBF * 54; f4i += 256) {
      int b = f4i / 54;
      int k4 = f4i - b * 54;
      *reinterpret_cast<float4*>(svec + b * 232 + k4 * 4) = src[f4i];
    }
  }
  if (tid < TBF) {
    const float* gf = gfeat + (size_t)(b0 + tid) * GLOBF;
    float gin[16];
#pragma unroll
    for (int i = 0; i < 16; ++i) gin[i] = gf[i];
    float g1[8];
#pragma unroll
    for (int j = 0; j < 8; ++j) {
      float acc = bg1[j];
#pragma unroll
      for (int i = 0; i < 16; ++i) acc = fmaf(gin[i], Wg1[i * 8 + j], acc);
      g1[j] = fmaxf(acc, 0.f);
    }
    float g2[8];
#pragma unroll
    for (int j = 0; j < 8; ++j) {
      float acc = bg2[j];
#pragma unroll
      for (int i = 0; i < 8; ++i) acc = fmaf(g1[i], Wg2[i * 8 + j], acc);
      g2[j] = fmaxf(acc, 0.f);
    }
#pragma unroll
    for (int j = 0; j < 16; ++j) {
      float acc = bg3[j];
#pragma unroll
      for (int i = 0; i < 8; ++i) acc = fmaf(g2[i], Wg3[i * 16 + j], acc);
      svec[tid * 232 + 216 + j] = fmaxf(acc, 0.f);
    }
  }
  __syncthreads();

  const int c0 = (tid & 31) * 4;
  const int rb = (tid >> 5) * 4;

  {
    const float* Wp = Wo1 + c0;
    float4 w0 = *reinterpret_cast<const float4*>(Wp + 0 * 128);
    float4 w1 = *reinterpret_cast<const float4*>(Wp + 1 * 128);
    float4 w2 = *reinterpret_cast<const float4*>(Wp + 2 * 128);
    float4 w3 = *reinterpret_cast<const float4*>(Wp + 3 * 128);
    float acc[4][4];
#pragma unroll
    for (int r = 0; r < 4; ++r)
#pragma unroll
      for (int c = 0; c < 4; ++c) acc[r][c] = 0.f;
    for (int i4 = 0; i4 < 58; ++i4) {
      float4 n0, n1, n2, n3;
      if (i4 < 57) {
        const float* Np = Wp + (size_t)(i4 * 4 + 4) * 128;
        n0 = *reinterpret_cast<const float4*>(Np + 0 * 128);
        n1 = *reinterpret_cast<const float4*>(Np + 1 * 128);
        n2 = *reinterpret_cast<const float4*>(Np + 2 * 128);
        n3 = *reinterpret_cast<const float4*>(Np + 3 * 128);
      }
#pragma unroll
      for (int r = 0; r < 4; ++r) {
        const float4 s = *reinterpret_cast<const float4*>(svec + (rb+r)*232 + i4*4);
        acc[r][0] = fmaf(s.x, w0.x, fmaf(s.y, w1.x, fmaf(s.z, w2.x, fmaf(s.w, w3.x, acc[r][0]))));
        acc[r][1] = fmaf(s.x, w0.y, fmaf(s.y, w1.y, fmaf(s.z, w2.y, fmaf(s.w, w3.y, acc[r][1]))));
        acc[r][2] = fmaf(s.x, w0.z, fmaf(s.y, w1.z, fmaf(s.z, w2.z, fmaf(s.w, w3.z, acc[r][2]))));
        acc[r][3] = fmaf(s.x, w0.w, fmaf(s.y, w1.w, fmaf(s.z, w2.w, fmaf(s.w, w3.w, acc[r][3]))));
      }
      w0 = n0; w1 = n1; w2 = n2; w3 = n3;
    }
    const float4 bv = *reinterpret_cast<const float4*>(bo1 + c0);
#pragma unroll
    for (int r = 0; r < 4; ++r) {
      float4 o;
      o.x = fmaxf(acc[r][0] + bv.x, 0.f);
      o.y = fmaxf(acc[r][1] + bv.y, 0.f);
      o.z = fmaxf(acc[r][2] + bv.z, 0.f);
      o.w = fmaxf(acc[r][3] + bv.w, 0.f);
      *reinterpret_cast<float4*>(sbuf1 + (rb + r) * 128 + c0) = o;
    }
  }
  __syncthreads();

  {
    const float* Wp = Wo2 + c0;
    float4 w0 = *reinterpret_cast<const float4*>(Wp + 0 * 128);
    float4 w1 = *reinterpret_cast<const float4*>(Wp + 1 * 128);
    float4 w2 = *reinterpret_cast<const float4*>(Wp + 2 * 128);
    float4 w3 = *reinterpret_cast<const float4*>(Wp + 3 * 128);
    float acc[4][4];
#pragma unroll
    for (int r = 0; r < 4; ++r)
#pragma unroll
      for (int c = 0; c < 4; ++c) acc[r][c] = 0.f;
    for (int i4 = 0; i4 < 32; ++i4) {
      float4 n0, n1, n2, n3;
      if (i4 < 31) {
        const float* Np = Wp + (size_t)(i4 * 4 + 4) * 128;
        n0 = *reinterpret_cast<const float4*>(Np + 0 * 128);
        n1 = *reinterpret_cast<const float4*>(Np + 1 * 128);
        n2 = *reinterpret_cast<const float4*>(Np + 2 * 128);
        n3 = *reinterpret_cast<const float4*>(Np + 3 * 128);
      }
#pragma unroll
      for (int r = 0; r < 4; ++r) {
        const float4 s = *reinterpret_cast<const float4*>(sbuf1 + (rb+r)*128 + i4*4);
        acc[r][0] = fmaf(s.x, w0.x, fmaf(s.y, w1.x, fmaf(s.z, w2.x, fmaf(s.w, w3.x, acc[r][0]))));
        acc[r][1] = fmaf(s.x, w0.y, fmaf(s.y, w1.y, fmaf(s.z, w2.y, fmaf(s.w, w3.y, acc[r][1]))));
        acc[r][2] = fmaf(s.x, w0.z, fmaf(s.y, w1.z, fmaf(s.z, w2.z, fmaf(s.w, w3.z, acc[r][2]))));
        acc[r][3] = fmaf(s.x, w0.w, fmaf(s.y, w1.w, fmaf(s.z, w2.w, fmaf(s.w, w3.w, acc[r][3]))));
      }
      w0 = n0; w1 = n1; w2 = n2; w3 = n3;
    }
    const float4 bv = *reinterpret_cast<const float4*>(bo2 + c0);
#pragma unroll
    for (int r = 0; r < 4; ++r) {
      float4 o;
      o.x = fmaxf(acc[r][0] + bv.x, 0.f);
      o.y = fmaxf(acc[r][1] + bv.y, 0.f);
      o.z = fmaxf(acc[r][2] + bv.z, 0.f);
      o.w = fmaxf(acc[r][3] + bv.w, 0.f);
      *reinterpret_cast<float4*>(sbuf2 + (rb + r) * 128 + c0) = o;
    }
  }
  __syncthreads();

  {
    const int c2 = (tid & 31) * 2;
    const float* Wp = Wo3 + c2;
    float2 w0 = *reinterpret_cast<const float2*>(Wp + 0 * 64);
    float2 w1 = *reinterpret_cast<const float2*>(Wp + 1 * 64);
    float2 w2 = *reinterpret_cast<const float2*>(Wp + 2 * 64);
    float2 w3 = *reinterpret_cast<const float2*>(Wp + 3 * 64);
    float acc[4][2];
#pragma unroll
    for (int r = 0; r < 4; ++r) { acc[r][0] = 0.f; acc[r][1] = 0.f; }
    for (int i4 = 0; i4 < 32; ++i4) {
      float2 n0, n1, n2, n3;
      if (i4 < 31) {
        const float* Np = Wp + (size_t)(i4 * 4 + 4) * 64;
        n0 = *reinterpret_cast<const float2*>(Np + 0 * 64);
        n1 = *reinterpret_cast<const float2*>(Np + 1 * 64);
        n2 = *reinterpret_cast<const float2*>(Np + 2 * 64);
        n3 = *reinterpret_cast<const float2*>(Np + 3 * 64);
      }
#pragma unroll
      for (int r = 0; r < 4; ++r) {
        const float4 s = *reinterpret_cast<const float4*>(sbuf2 + (rb+r)*128 + i4*4);
        acc[r][0] = fmaf(s.x, w0.x, fmaf(s.y, w1.x, fmaf(s.z, w2.x, fmaf(s.w, w3.x, acc[r][0]))));
        acc[r][1] = fmaf(s.x, w0.y, fmaf(s.y, w1.y, fmaf(s.z, w2.y, fmaf(s.w, w3.y, acc[r][1]))));
      }
      w0 = n0; w1 = n1; w2 = n2; w3 = n3;
    }
    const float2 bv = *reinterpret_cast<const float2*>(bo3 + c2);
#pragma unroll
    for (int r = 0; r < 4; ++r) {
      float2 o;
      o.x = acc[r][0] + bv.x;
      o.y = acc[r][1] + bv.y;
      *reinterpret_cast<float2*>(out + (size_t)(b0 + rb + r) * 64 + c2) = o;
    }
  }
}

// ---------------------------------------------------------------------------
extern "C" void kernel_launch(void* const* d_in, const int* in_sizes, int n_in,
                              void* d_out, int out_size, void* d_ws, size_t ws_size,
                              hipStream_t stream) {
  const float* x      = (const float*)d_in[0];
  const int*   ei     = (const int*)d_in[1];
  const float* ea     = (const float*)d_in[2];
  const float* gfeat  = (const float*)d_in[3];
  const float* W1_rel = (const float*)d_in[5];
  const float* b1     = (const float*)d_in[6];
  const float* W1_root= (const float*)d_in[7];
  const float* W2_rel = (const float*)d_in[8];
  const float* b2     = (const float*)d_in[9];
  const float* W2_root= (const float*)d_in[10];
  const float* Wg1 = (const float*)d_in[11];
  const float* bg1 = (const float*)d_in[12];
  const float* Wg2 = (const float*)d_in[13];
  const float* bg2 = (const float*)d_in[14];
  const float* Wg3 = (const float*)d_in[15];
  const float* bg3 = (const float*)d_in[16];
  const float* Wo1 = (const float*)d_in[17];
  const float* bo1 = (const float*)d_in[18];
  const float* Wo2 = (const float*)d_in[19];
  const float* bo2 = (const float*)d_in[20];
  const float* Wo3 = (const float*)d_in[21];
  const float* bo3 = (const float*)d_in[22];
  float* outp = (float*)d_out;

  // workspace (~166 MB)
  uint2*    rec    = (uint2*)d_ws;                         // NE*8B
  uint2*    recA   = rec + NE;                             // NE*8B
  unsigned char* dhiA = (unsigned char*)(recA + NE);       // NE*1B
  float*    z2     = (float*)(dhiA + NE);                  // NN*4 f
  float*    r2     = z2 + (size_t)NN * 4;                  // NN*4 f
  float*    embeds = r2 + (size_t)NN * 4;                  // NN*4 f
  unsigned* hist   = (unsigned*)(embeds + (size_t)NN * 4); // NBK
  unsigned* base   = hist + NBK;                           // NBK+1
  unsigned* cursorB= base + NBK + 1;                       // NBK
  unsigned* curA   = cursorB + NBK;                        // NCL

  hipMemsetAsync(hist, 0, NBK * sizeof(unsigned), stream);
  k_histl <<<HB, 256, 0, stream>>>(ei, hist);
  k_scan2 <<<1, 1024, 0, stream>>>(hist, base, cursorB, curA);
  k_placeA<<<NBA, 256, 0, stream>>>(ei, ea, curA, recA, dhiA);
  k_placeB<<<NCL * CPB, 256, 0, stream>>>(recA, dhiA, base, cursorB, rec);
  k_conv1s<<<NBK, 256, 0, stream>>>(rec, base, x, W1_rel, b1, W1_root,
                                    W2_rel, b2, W2_root, z2, r2);
  k_conv2s<<<NBK, 256, 0, stream>>>(rec, base, z2, r2, embeds);
  k_final <<<BD / TBF, 256, 0, stream>>>(embeds, gfeat,
                                         Wg1, bg1, Wg2, bg2, Wg3, bg3,
                                         Wo1, bo1, Wo2, bo2, Wo3, bo3, outp);
}